// Round 1
// 423.079 us; speedup vs baseline: 1.0959x; 1.0959x over previous
//
#include <hip/hip_runtime.h>

typedef unsigned short u16;
typedef unsigned int u32;
typedef float f32x4 __attribute__((ext_vector_type(4)));
typedef short i16x8 __attribute__((ext_vector_type(8)));
typedef __bf16 bf16x8_t __attribute__((ext_vector_type(8)));

#define LQ 43054

__device__ __forceinline__ float bf2f(u16 u) {
  union { u32 i; float f; } v; v.i = ((u32)u) << 16; return v.f;
}
__device__ __forceinline__ u16 f2bf(float f) {
  u32 i = __float_as_uint(f);
  return (u16)((i + 0x7FFFu + ((i >> 16) & 1u)) >> 16);
}

// ---- MFMA wrapper robust to builtin operand type (V8 short vs V8 __bf16) ----
template <typename T>
__device__ __forceinline__ auto mfma_try(T a, T b, f32x4 c, int)
    -> decltype(__builtin_amdgcn_mfma_f32_16x16x32_bf16(a, b, c, 0, 0, 0)) {
  return __builtin_amdgcn_mfma_f32_16x16x32_bf16(a, b, c, 0, 0, 0);
}
template <typename T>
__device__ __forceinline__ f32x4 mfma_try(T a, T b, f32x4 c, long) {
  return __builtin_amdgcn_mfma_f32_16x16x32_bf16(
      __builtin_bit_cast(bf16x8_t, a), __builtin_bit_cast(bf16x8_t, b), c, 0, 0, 0);
}
__device__ __forceinline__ f32x4 mfma_bf16(i16x8 a, i16x8 b, f32x4 c) {
  return mfma_try(a, b, c, 0);
}

// ---- all 6 weight transposes in one kernel: f32 (256 x N) -> bf16 (N x 256) ----
__global__ void transpose_all_kernel(
    const float* __restrict__ w_off, const float* __restrict__ w_attn,
    const float* __restrict__ w_val, const float* __restrict__ w_out,
    const float* __restrict__ w1, const float* __restrict__ w2,
    u16* __restrict__ wT) {
  int b = blockIdx.x;
  const float* src; u16* dst; int N; int col;
  if (b < 256)       { src = w_off;  dst = wT;          N = 256; col = b; }
  else if (b < 384)  { src = w_attn; dst = wT + 65536;  N = 128; col = b - 256; }
  else if (b < 640)  { src = w_val;  dst = wT + 98304;  N = 256; col = b - 384; }
  else if (b < 896)  { src = w_out;  dst = wT + 163840; N = 256; col = b - 640; }
  else if (b < 1152) { src = w1;     dst = wT + 229376; N = 256; col = b - 896; }
  else               { src = w2;     dst = wT + 294912; N = 256; col = b - 1152; }
  dst[col * 256 + threadIdx.x] = f2bf(src[threadIdx.x * N + col]);
}

// ================= shared helpers ==========================================
__device__ __forceinline__ void stage_a_bf16(uint4* As, const u16* A, int r0, int M, int tid) {
#pragma unroll
  for (int it = 0; it < 8; ++it) {
    int e = tid + it * 256;
    int row = e >> 5, c = e & 31;
    int gr = r0 + row;
    uint4 v = make_uint4(0u, 0u, 0u, 0u);
    if (gr < M) v = ((const uint4*)A)[gr * 32 + c];
    As[row * 32 + (c ^ (row & 7))] = v;
  }
}
template <int ADD>
__device__ __forceinline__ void stage_a_f32(uint4* As, const float* A, const float* A2,
                                            int r0, int M, int tid) {
#pragma unroll
  for (int it = 0; it < 16; ++it) {
    int e = tid + it * 256;
    int row = e >> 6, c4 = e & 63;
    int gr = r0 + row;
    float4 v = make_float4(0.f, 0.f, 0.f, 0.f);
    if (gr < M) {
      v = ((const float4*)A)[gr * 64 + c4];
      if constexpr (ADD) {
        float4 p = ((const float4*)A2)[gr * 64 + c4];
        v.x += p.x; v.y += p.y; v.z += p.z; v.w += p.w;
      }
    }
    uint2 pk;
    pk.x = (u32)f2bf(v.x) | ((u32)f2bf(v.y) << 16);
    pk.y = (u32)f2bf(v.z) | ((u32)f2bf(v.w) << 16);
    int c = c4 >> 1, hf = c4 & 1;
    ((uint2*)As)[((row * 32 + (c ^ (row & 7))) << 1) | hf] = pk;
  }
}
// load one 16-col B tile's 8 K-fragments into registers
__device__ __forceinline__ void load_b(i16x8* f, const u16* Bt, int t, int l16, int quad) {
  const uint4* bp = (const uint4*)Bt + (t * 16 + l16) * 32 + quad;
#pragma unroll
  for (int kk = 0; kk < 8; ++kk) f[kk] = __builtin_bit_cast(i16x8, bp[kk << 2]);
}
// 32 MFMAs of one tile over all 4 row-groups, A from LDS
__device__ __forceinline__ void tile_mfma(f32x4* acc, const uint4* As,
                                          const i16x8* bfr, int l16, int quad) {
#pragma unroll
  for (int rg = 0; rg < 4; ++rg) {
    int arow = rg * 16 + l16;
    f32x4 a = {0.f, 0.f, 0.f, 0.f};
#pragma unroll
    for (int kk = 0; kk < 8; ++kk) {
      i16x8 afr = __builtin_bit_cast(i16x8, As[arow * 32 + (((kk << 2) + quad) ^ (arow & 7))]);
      a = mfma_bf16(afr, bfr[kk], a);
    }
    acc[rg] = a;
  }
}

// LDS output staging: u16 rows with stride 264 (528 B: 16B-aligned, bank-skewed).
// 64 rows x 264 u16 = 33792 B -> fits in the 2176-uint4 (34816 B) As buffer.
#define LS_STRIDE 264
// vectorized store: each iteration a wave writes 2 complete 512-B rows (dwordx4/lane)
__device__ __forceinline__ void lds_store_rows(const u16* Ls, u16* out,
                                               int r0, int M, int w, int lane) {
#pragma unroll
  for (int it = 0; it < 8; ++it) {
    int lrow = w * 16 + it * 2 + (lane >> 5);
    int grow = r0 + lrow;
    int chunk = lane & 31;
    if (grow < M) {
      *(uint4*)(out + (size_t)grow * 256 + chunk * 8) =
          *(const uint4*)(Ls + lrow * LS_STRIDE + chunk * 8);
    }
  }
}

// ---- generic GEMM: wave owns 4 col-tiles, sweeps all 64 rows ----
// AIN: 0 = A f32, 2 = A bf16.  MODE: 1 = bf16, 2 = relu+bf16.  N fixed at 256.
template <int AIN, int MODE, int NT>
__global__ __launch_bounds__(256, 3) void gemm_kernel(
    const void* __restrict__ Av, const u16* __restrict__ Bt,
    const float* __restrict__ bias, void* __restrict__ out, int M) {
  __shared__ uint4 As[2176];
  const int tid = threadIdx.x;
  const int w = tid >> 6, lane = tid & 63, quad = lane >> 4, l16 = lane & 15;
  const int r0 = blockIdx.x * 64;
  if constexpr (AIN == 2) stage_a_bf16(As, (const u16*)Av, r0, M, tid);
  else                    stage_a_f32<0>(As, (const float*)Av, nullptr, r0, M, tid);
  __syncthreads();
  i16x8 bfr[2][8];
  load_b(bfr[0], Bt, w * 4, l16, quad);
  f32x4 vals[4][4];
#pragma unroll
  for (int i = 0; i < 4; ++i) {
    const int t = w * 4 + i;
    if (i + 1 < 4) load_b(bfr[(i + 1) & 1], Bt, t + 1, l16, quad);
    tile_mfma(vals[i], As, bfr[i & 1], l16, quad);
  }
  // ---- vectorized epilogue: regs -> LDS (transpose) -> dwordx4 stores ----
  __syncthreads();  // all waves done reading As
  u16* Ls = (u16*)As;
#pragma unroll
  for (int i = 0; i < 4; ++i) {
    const int col = (w * 4 + i) * 16 + l16;
    const float bv = bias[col];
#pragma unroll
    for (int rg = 0; rg < 4; ++rg)
#pragma unroll
      for (int r = 0; r < 4; ++r) {
        float v = vals[i][rg][r] + bv;
        if (MODE == 2) v = fmaxf(v, 0.f);
        Ls[(rg * 16 + (quad << 2) + r) * LS_STRIDE + col] = f2bf(v);
      }
  }
  __syncthreads();
  lds_store_rows(Ls, (u16*)out, r0, M, w, lane);
}

// ---- fused offsets + attention-softmax GEMM: A = bf16(query + pos) ----
// 24 tiles; wave w owns tiles {w, w+4, ..., w+20}. Tiles 0..15 -> offb bf16
// (vectorized epilogue); 16..23 -> softmax -> aw f32 (scalar, already 64B lines).
__global__ __launch_bounds__(256, 3) void offaw_gemm_kernel(
    const float* __restrict__ query, const float* __restrict__ pos,
    const u16* __restrict__ Bt, const float* __restrict__ b_off,
    const float* __restrict__ b_attn, u16* __restrict__ offb,
    float* __restrict__ aw, int M) {
  __shared__ uint4 As[2176];
  const int tid = threadIdx.x;
  const int w = tid >> 6, lane = tid & 63, quad = lane >> 4, l16 = lane & 15;
  const int r0 = blockIdx.x * 64;
  stage_a_f32<1>(As, query, pos, r0, M, tid);
  __syncthreads();
  i16x8 bfr[2][8];
  load_b(bfr[0], Bt, w, l16, quad);
  f32x4 vals[4][4];
#pragma unroll
  for (int i = 0; i < 6; ++i) {
    const int t = w + 4 * i;
    if (i + 1 < 6) load_b(bfr[(i + 1) & 1], Bt, w + 4 * (i + 1), l16, quad);
    if (i < 4) {
      tile_mfma(vals[i], As, bfr[i & 1], l16, quad);
    } else {
      f32x4 acc[4];
      tile_mfma(acc, As, bfr[i & 1], l16, quad);
      const int colc = (t - 16) * 16 + l16;
      const float bv = b_attn[colc];
#pragma unroll
      for (int rg = 0; rg < 4; ++rg)
#pragma unroll
        for (int r = 0; r < 4; ++r) {
          float v = acc[rg][r] + bv;
          float m = v;
#pragma unroll
          for (int o = 1; o < 16; o <<= 1) m = fmaxf(m, __shfl_xor(m, o));
          float e = __expf(v - m);
          float s = e;
#pragma unroll
          for (int o = 1; o < 16; o <<= 1) s += __shfl_xor(s, o);
          int row = r0 + rg * 16 + (quad << 2) + r;
          if (row < M) aw[row * 128 + colc] = e / s;
        }
    }
  }
  // ---- vectorized offb epilogue ----
  __syncthreads();
  u16* Ls = (u16*)As;
#pragma unroll
  for (int i = 0; i < 4; ++i) {
    const int col = (w + 4 * i) * 16 + l16;
    const float bv = b_off[col];
#pragma unroll
    for (int rg = 0; rg < 4; ++rg)
#pragma unroll
      for (int r = 0; r < 4; ++r)
        Ls[(rg * 16 + (quad << 2) + r) * LS_STRIDE + col] = f2bf(vals[i][rg][r] + bv);
  }
  __syncthreads();
  lds_store_rows(Ls, offb, r0, M, w, lane);
}

// ---- GEMM + residual + LayerNorm; cross-wave LN partials through LDS ----
// RBF: resid bf16 if 1 else f32.  OBF: out bf16 (vectorized) if 1 else f32 (scalar).
template <int RBF, int OBF>
__global__ __launch_bounds__(256, 2) void gemm_ln_kernel(
    const u16* __restrict__ A, const u16* __restrict__ Bt,
    const float* __restrict__ bias, const void* __restrict__ residv,
    const float* __restrict__ g, const float* __restrict__ beta,
    void* __restrict__ outv, int M) {
  __shared__ uint4 As[2176];
  __shared__ float2 pnorm[256];  // [row][wave] partial {s, s2}
  const int tid = threadIdx.x;
  const int w = tid >> 6, lane = tid & 63, quad = lane >> 4, l16 = lane & 15;
  const int r0 = blockIdx.x * 64;
  stage_a_bf16(As, A, r0, M, tid);
  __syncthreads();
  i16x8 bfr[2][8];
  load_b(bfr[0], Bt, w * 4, l16, quad);
  f32x4 vals[4][4];  // [tile][rg]
#pragma unroll
  for (int i = 0; i < 4; ++i) {
    const int t = w * 4 + i;
    if (i + 1 < 4) load_b(bfr[(i + 1) & 1], Bt, t + 1, l16, quad);
    tile_mfma(vals[i], As, bfr[i & 1], l16, quad);
  }
  // bias + residual + stats
  float s[16], s2[16];
#pragma unroll
  for (int k = 0; k < 16; ++k) { s[k] = 0.f; s2[k] = 0.f; }
#pragma unroll
  for (int i = 0; i < 4; ++i) {
    const int col = (w * 4 + i) * 16 + l16;
    const float bv = bias[col];
#pragma unroll
    for (int rg = 0; rg < 4; ++rg)
#pragma unroll
      for (int r = 0; r < 4; ++r) {
        int row = r0 + rg * 16 + (quad << 2) + r;
        float rv = 0.f;
        if (row < M) rv = RBF ? bf2f(((const u16*)residv)[row * 256 + col])
                              : ((const float*)residv)[row * 256 + col];
        float v = vals[i][rg][r] + bv + rv;
        vals[i][rg][r] = v;
        s[rg * 4 + r] += v; s2[rg * 4 + r] += v * v;
      }
  }
  // reduce over the 16 l16 lanes (this wave's 64 cols), publish partials
#pragma unroll
  for (int k = 0; k < 16; ++k)
#pragma unroll
    for (int o = 1; o < 16; o <<= 1) {
      s[k] += __shfl_xor(s[k], o);
      s2[k] += __shfl_xor(s2[k], o);
    }
  if (l16 == 0) {
#pragma unroll
    for (int rg = 0; rg < 4; ++rg)
#pragma unroll
      for (int r = 0; r < 4; ++r) {
        int lrow = rg * 16 + (quad << 2) + r;
        pnorm[lrow * 4 + w] = make_float2(s[rg * 4 + r], s2[rg * 4 + r]);
      }
  }
  __syncthreads();
  // combine 4 wave-partials, normalize, store
  if constexpr (OBF) {
    u16* Ls = (u16*)As;  // As reads all completed before the pnorm barrier
#pragma unroll
    for (int rg = 0; rg < 4; ++rg)
#pragma unroll
      for (int r = 0; r < 4; ++r) {
        int lrow = rg * 16 + (quad << 2) + r;
        float4 p01 = ((const float4*)pnorm)[lrow * 2];
        float4 p23 = ((const float4*)pnorm)[lrow * 2 + 1];
        float ss = p01.x + p01.z + p23.x + p23.z;
        float qq = p01.y + p01.w + p23.y + p23.w;
        float mean = ss * (1.f / 256.f);
        float var = qq * (1.f / 256.f) - mean * mean;
        float inv = rsqrtf(var + 1e-5f);
#pragma unroll
        for (int i = 0; i < 4; ++i) {
          const int col = (w * 4 + i) * 16 + l16;
          float o = (vals[i][rg][r] - mean) * inv * g[col] + beta[col];
          Ls[lrow * LS_STRIDE + col] = f2bf(o);
        }
      }
    __syncthreads();
    lds_store_rows(Ls, (u16*)outv, r0, M, w, lane);
  } else {
#pragma unroll
    for (int rg = 0; rg < 4; ++rg)
#pragma unroll
      for (int r = 0; r < 4; ++r) {
        int lrow = rg * 16 + (quad << 2) + r;
        float4 p01 = ((const float4*)pnorm)[lrow * 2];
        float4 p23 = ((const float4*)pnorm)[lrow * 2 + 1];
        float ss = p01.x + p01.z + p23.x + p23.z;
        float qq = p01.y + p01.w + p23.y + p23.w;
        float mean = ss * (1.f / 256.f);
        float var = qq * (1.f / 256.f) - mean * mean;
        float inv = rsqrtf(var + 1e-5f);
        int row = r0 + lrow;
        if (row < M) {
#pragma unroll
          for (int i = 0; i < 4; ++i) {
            const int col = (w * 4 + i) * 16 + l16;
            float o = (vals[i][rg][r] - mean) * inv * g[col] + beta[col];
            ((float*)outv)[row * 256 + col] = o;
          }
        }
      }
  }
}

// ---- fused prep + deformable sampling: one block = 2 queries (unchanged) ----
__global__ __launch_bounds__(256) void sampler_kernel(
    const float* __restrict__ refp, const u16* __restrict__ offb,
    const float* __restrict__ aw, const u16* __restrict__ value,
    u32* __restrict__ accv) {
  __shared__ uint4 rec[272];
  const int t = threadIdx.x;
  const int b = blockIdx.x;
  {
    const int qs = t >> 7, j = t & 127;
    const int i = b * 2 + qs;
    const int h = j >> 4, lp = j & 15, l = lp >> 2;
    const int Wl = (l == 0) ? 180 : (l == 1) ? 90 : (l == 2) ? 45 : 23;
    const int st = (l == 0) ? 0 : (l == 1) ? 32400 : (l == 2) ? 40500 : 42525;
    const float wj = aw[i * 128 + j];
    const u32 o2 = *(const u32*)(offb + i * 256 + h * 32 + lp * 2);
    const float ox = bf2f((u16)(o2 & 0xffffu)), oy = bf2f((u16)(o2 >> 16));
    const float rx = refp[i * 8 + l * 2], ry = refp[i * 8 + l * 2 + 1];
    float x = rx * (float)Wl + ox - 0.5f;
    float y = ry * (float)Wl + oy - 0.5f;
    float x0f = floorf(x), y0f = floorf(y);
    float fx = x - x0f, fy = y - y0f;
    int x0 = (int)x0f, y0 = (int)y0f;
    bool vx0 = (x0 >= 0) & (x0 < Wl), vx1 = (x0 + 1 >= 0) & (x0 + 1 < Wl);
    bool vy0 = (y0 >= 0) & (y0 < Wl), vy1 = (y0 + 1 >= 0) & (y0 + 1 < Wl);
    int x0c = min(max(x0, 0), Wl - 1), x1c = min(max(x0 + 1, 0), Wl - 1);
    int y0c = min(max(y0, 0), Wl - 1), y1c = min(max(y0 + 1, 0), Wl - 1);
    float w00 = (vx0 & vy0) ? wj * (1.f - fx) * (1.f - fy) : 0.f;
    float w01 = (vx1 & vy0) ? wj * fx * (1.f - fy) : 0.f;
    float w10 = (vx0 & vy1) ? wj * (1.f - fx) * fy : 0.f;
    float w11 = (vx1 & vy1) ? wj * fx * fy : 0.f;
    uint4 r;
    r.x = (u32)((st + y0c * Wl + x0c) * 512 + h * 64) | (u32)(x1c - x0c);
    r.y = (u32)(y1c - y0c) * (u32)(Wl * 512);
    r.z = (u32)f2bf(w00) | ((u32)f2bf(w01) << 16);
    r.w = (u32)f2bf(w10) | ((u32)f2bf(w11) << 16);
    rec[qs * 136 + h * 17 + lp] = r;
  }
  __syncthreads();
  const int qs = t >> 7, j = t & 127;
  const int h = j >> 4, dp = j & 15;
  const char* vb = (const char*)value;
  float a0 = 0.f, a1 = 0.f;
  const int rbase = qs * 136 + h * 17;
#pragma unroll
  for (int p = 0; p < 16; ++p) {
    uint4 r = rec[rbase + p];
    u32 base = (r.x & 0xFFFFFFFEu) + (u32)(dp * 4);
    u32 dxo = (r.x & 1u) << 9;
    u32 dyo = r.y;
    float w00 = __uint_as_float(r.z << 16);
    float w01 = __uint_as_float(r.z & 0xFFFF0000u);
    float w10 = __uint_as_float(r.w << 16);
    float w11 = __uint_as_float(r.w & 0xFFFF0000u);
    u32 p00 = *(const u32*)(vb + base);
    u32 p01 = *(const u32*)(vb + base + dxo);
    u32 p10 = *(const u32*)(vb + base + dyo);
    u32 p11 = *(const u32*)(vb + base + dyo + dxo);
    a0 = fmaf(w00, __uint_as_float(p00 << 16), a0);
    a1 = fmaf(w00, __uint_as_float(p00 & 0xFFFF0000u), a1);
    a0 = fmaf(w01, __uint_as_float(p01 << 16), a0);
    a1 = fmaf(w01, __uint_as_float(p01 & 0xFFFF0000u), a1);
    a0 = fmaf(w10, __uint_as_float(p10 << 16), a0);
    a1 = fmaf(w10, __uint_as_float(p10 & 0xFFFF0000u), a1);
    a0 = fmaf(w11, __uint_as_float(p11 << 16), a0);
    a1 = fmaf(w11, __uint_as_float(p11 & 0xFFFF0000u), a1);
  }
  u32 pk = (u32)f2bf(a0) | ((u32)f2bf(a1) << 16);
  accv[(b * 2 + qs) * 128 + j] = pk;
}

extern "C" void kernel_launch(void* const* d_in, const int* in_sizes, int n_in,
                              void* d_out, int out_size, void* d_ws, size_t ws_size,
                              hipStream_t stream) {
  const float* query  = (const float*)d_in[0];
  const float* refp   = (const float*)d_in[1];
  const float* pos    = (const float*)d_in[2];
  const float* w_off  = (const float*)d_in[5];
  const float* b_off  = (const float*)d_in[6];
  const float* w_attn = (const float*)d_in[7];
  const float* b_attn = (const float*)d_in[8];
  const float* w_val  = (const float*)d_in[9];
  const float* b_val  = (const float*)d_in[10];
  const float* w_out  = (const float*)d_in[11];
  const float* b_out  = (const float*)d_in[12];
  const float* g1     = (const float*)d_in[13];
  const float* beta1  = (const float*)d_in[14];
  const float* w1     = (const float*)d_in[15];
  const float* b1     = (const float*)d_in[16];
  const float* w2     = (const float*)d_in[17];
  const float* b2     = (const float*)d_in[18];
  const float* g2     = (const float*)d_in[19];
  const float* beta2  = (const float*)d_in[20];

  char* ws = (char*)d_ws;
  u16*   wT    = (u16*)(ws + 0);            //   720,896, live whole launch
  u16*   value = (u16*)(ws + 720896);       // 22,043,648  dead after sampler
  u16*   offb  = (u16*)(ws + 22764544);     // 22,043,648  dead after sampler
  float* aw    = (float*)(ws + 44808192);   // 22,043,648  dead after sampler
  u16*   accb  = (u16*)(ws + 66851840);     // 22,043,648  dead after out-proj
  u16*   xb    = (u16*)(ws + 720896);       // over value (dead)
  u16*   hb    = (u16*)(ws + 22764544);     // over offb (dead)

  u16* woffT  = wT;                // 256 rows; wattnT contiguous after (384-row B)
  u16* wvalT  = wT + 98304;
  u16* woutT  = wT + 163840;
  u16* w1T    = wT + 229376;
  u16* w2T    = wT + 294912;

  transpose_all_kernel<<<1408, 256, 0, stream>>>(w_off, w_attn, w_val, w_out, w1, w2, wT);

  const int gm = (LQ + 63) / 64;  // 673
  gemm_kernel<0, 1, 4><<<gm, 256, 0, stream>>>(query, wvalT, b_val, value, LQ);
  offaw_gemm_kernel<<<gm, 256, 0, stream>>>(query, pos, woffT, b_off, b_attn, offb, aw, LQ);
  sampler_kernel<<<LQ / 2, 256, 0, stream>>>(refp, offb, aw, value, (u32*)accb);
  gemm_ln_kernel<0, 1><<<gm, 256, 0, stream>>>(accb, woutT, b_out, query, g1, beta1, xb, LQ);
  gemm_kernel<2, 2, 4><<<gm, 256, 0, stream>>>(xb, w1T, b1, hb, LQ);
  gemm_ln_kernel<1, 0><<<gm, 256, 0, stream>>>(hb, w2T, b2, xb, g2, beta2, d_out, LQ);
}

// Round 2
// 419.267 us; speedup vs baseline: 1.1059x; 1.0091x over previous
//
#include <hip/hip_runtime.h>

typedef unsigned short u16;
typedef unsigned int u32;
typedef float f32x4 __attribute__((ext_vector_type(4)));
typedef short i16x8 __attribute__((ext_vector_type(8)));
typedef __bf16 bf16x8_t __attribute__((ext_vector_type(8)));

#define LQ 43054

__device__ __forceinline__ float bf2f(u16 u) {
  union { u32 i; float f; } v; v.i = ((u32)u) << 16; return v.f;
}
__device__ __forceinline__ u16 f2bf(float f) {
  u32 i = __float_as_uint(f);
  return (u16)((i + 0x7FFFu + ((i >> 16) & 1u)) >> 16);
}

// D = S0.lo*S1.lo + S0.hi*S1.hi + S2  (bf16 pairs, f32 accumulate)
__device__ __forceinline__ float dot2bf(u32 v, u32 w, float c) {
  float d;
  asm("v_dot2_f32_bf16 %0, %1, %2, %3" : "=v"(d) : "v"(v), "v"(w), "v"(c));
  return d;
}

// ---- MFMA wrapper robust to builtin operand type (V8 short vs V8 __bf16) ----
template <typename T>
__device__ __forceinline__ auto mfma_try(T a, T b, f32x4 c, int)
    -> decltype(__builtin_amdgcn_mfma_f32_16x16x32_bf16(a, b, c, 0, 0, 0)) {
  return __builtin_amdgcn_mfma_f32_16x16x32_bf16(a, b, c, 0, 0, 0);
}
template <typename T>
__device__ __forceinline__ f32x4 mfma_try(T a, T b, f32x4 c, long) {
  return __builtin_amdgcn_mfma_f32_16x16x32_bf16(
      __builtin_bit_cast(bf16x8_t, a), __builtin_bit_cast(bf16x8_t, b), c, 0, 0, 0);
}
__device__ __forceinline__ f32x4 mfma_bf16(i16x8 a, i16x8 b, f32x4 c) {
  return mfma_try(a, b, c, 0);
}

// ---- all 6 weight transposes in one kernel: f32 (256 x N) -> bf16 (N x 256) ----
__global__ void transpose_all_kernel(
    const float* __restrict__ w_off, const float* __restrict__ w_attn,
    const float* __restrict__ w_val, const float* __restrict__ w_out,
    const float* __restrict__ w1, const float* __restrict__ w2,
    u16* __restrict__ wT) {
  int b = blockIdx.x;
  const float* src; u16* dst; int N; int col;
  if (b < 256)       { src = w_off;  dst = wT;          N = 256; col = b; }
  else if (b < 384)  { src = w_attn; dst = wT + 65536;  N = 128; col = b - 256; }
  else if (b < 640)  { src = w_val;  dst = wT + 98304;  N = 256; col = b - 384; }
  else if (b < 896)  { src = w_out;  dst = wT + 163840; N = 256; col = b - 640; }
  else if (b < 1152) { src = w1;     dst = wT + 229376; N = 256; col = b - 896; }
  else               { src = w2;     dst = wT + 294912; N = 256; col = b - 1152; }
  dst[col * 256 + threadIdx.x] = f2bf(src[threadIdx.x * N + col]);
}

// ================= shared helpers ==========================================
// DMA staging for bf16 A: linear LDS dest, XOR-swizzle applied to the per-lane
// GLOBAL source column (involution; reads recover A[row][col] exactly).
// Tail rows are clamped to M-1: garbage values only ever feed output rows >= M,
// which are never stored (and LN stats are strictly per-row).
__device__ __forceinline__ void stage_a_dma(uint4* As, const u16* A, int r0, int M,
                                            int w, int lane) {
#pragma unroll
  for (int jj = 0; jj < 8; ++jj) {
    int row = w * 16 + jj * 2 + (lane >> 5);
    int gr = min(r0 + row, M - 1);
    int c = lane & 31;
    const uint4* gp = (const uint4*)A + (size_t)gr * 32 + (c ^ (row & 7));
    __builtin_amdgcn_global_load_lds(
        (const __attribute__((address_space(1))) void*)gp,
        (__attribute__((address_space(3))) void*)(As + (w * 16 + jj * 2) * 32),
        16, 0, 0);
  }
}
// f32 staging, phased: issue IT loads, then convert+write (keeps 8 loads in flight)
template <int ADD, int PH>
__device__ __forceinline__ void stage_a_f32(uint4* As, const float* A, const float* A2,
                                            int r0, int M, int tid) {
  constexpr int IT = 16 / PH;
#pragma unroll
  for (int h = 0; h < PH; ++h) {
    float4 va[IT];
    float4 vp[ADD ? IT : 1];
#pragma unroll
    for (int it = 0; it < IT; ++it) {
      int e = tid + (h * IT + it) * 256;
      int gr = min(r0 + (e >> 6), M - 1);
      int idx = gr * 64 + (e & 63);
      va[it] = ((const float4*)A)[idx];
      if constexpr (ADD) vp[it] = ((const float4*)A2)[idx];
    }
#pragma unroll
    for (int it = 0; it < IT; ++it) {
      int e = tid + (h * IT + it) * 256;
      int row = e >> 6, c4 = e & 63;
      float4 v = va[it];
      if constexpr (ADD) {
        v.x += vp[it].x; v.y += vp[it].y; v.z += vp[it].z; v.w += vp[it].w;
      }
      uint2 pk;
      pk.x = (u32)f2bf(v.x) | ((u32)f2bf(v.y) << 16);
      pk.y = (u32)f2bf(v.z) | ((u32)f2bf(v.w) << 16);
      int c = c4 >> 1, hf = c4 & 1;
      ((uint2*)As)[((row * 32 + (c ^ (row & 7))) << 1) | hf] = pk;
    }
  }
}
// load one 16-col B tile's 8 K-fragments into registers
__device__ __forceinline__ void load_b(i16x8* f, const u16* Bt, int t, int l16, int quad) {
  const uint4* bp = (const uint4*)Bt + (t * 16 + l16) * 32 + quad;
#pragma unroll
  for (int kk = 0; kk < 8; ++kk) f[kk] = __builtin_bit_cast(i16x8, bp[kk << 2]);
}
// 32 MFMAs of one tile over all 4 row-groups, A from LDS
__device__ __forceinline__ void tile_mfma(f32x4* acc, const uint4* As,
                                          const i16x8* bfr, int l16, int quad) {
#pragma unroll
  for (int rg = 0; rg < 4; ++rg) {
    int arow = rg * 16 + l16;
    f32x4 a = {0.f, 0.f, 0.f, 0.f};
#pragma unroll
    for (int kk = 0; kk < 8; ++kk) {
      i16x8 afr = __builtin_bit_cast(i16x8, As[arow * 32 + (((kk << 2) + quad) ^ (arow & 7))]);
      a = mfma_bf16(afr, bfr[kk], a);
    }
    acc[rg] = a;
  }
}

// LDS output staging: u16 rows with stride 264 (528 B: 16B-aligned, bank-skewed).
#define LS_STRIDE 264
// vectorized store: each iteration a wave writes 2 complete 512-B rows (dwordx4/lane)
__device__ __forceinline__ void lds_store_rows(const u16* Ls, u16* out,
                                               int r0, int M, int w, int lane) {
#pragma unroll
  for (int it = 0; it < 8; ++it) {
    int lrow = w * 16 + it * 2 + (lane >> 5);
    int grow = r0 + lrow;
    int chunk = lane & 31;
    if (grow < M) {
      *(uint4*)(out + (size_t)grow * 256 + chunk * 8) =
          *(const uint4*)(Ls + lrow * LS_STRIDE + chunk * 8);
    }
  }
}

// ---- generic GEMM: wave owns 4 col-tiles, sweeps all 64 rows ----
// AIN: 0 = A f32, 2 = A bf16 (DMA).  MODE: 1 = bf16, 2 = relu+bf16.
template <int AIN, int MODE>
__global__ __launch_bounds__(256, 3) void gemm_kernel(
    const void* __restrict__ Av, const u16* __restrict__ Bt,
    const float* __restrict__ bias, void* __restrict__ out, int M) {
  __shared__ uint4 As[2176];
  const int tid = threadIdx.x;
  const int w = tid >> 6, lane = tid & 63, quad = lane >> 4, l16 = lane & 15;
  const int r0 = blockIdx.x * 64;
  if constexpr (AIN == 2) stage_a_dma(As, (const u16*)Av, r0, M, w, lane);
  else                    stage_a_f32<0, 2>(As, (const float*)Av, nullptr, r0, M, tid);
  __syncthreads();
  i16x8 bfr[2][8];
  load_b(bfr[0], Bt, w * 4, l16, quad);
  f32x4 vals[4][4];
#pragma unroll
  for (int i = 0; i < 4; ++i) {
    const int t = w * 4 + i;
    if (i + 1 < 4) load_b(bfr[(i + 1) & 1], Bt, t + 1, l16, quad);
    tile_mfma(vals[i], As, bfr[i & 1], l16, quad);
  }
  // ---- vectorized epilogue: regs -> LDS (transpose) -> dwordx4 stores ----
  __syncthreads();  // all waves done reading As
  u16* Ls = (u16*)As;
#pragma unroll
  for (int i = 0; i < 4; ++i) {
    const int col = (w * 4 + i) * 16 + l16;
    const float bv = bias[col];
#pragma unroll
    for (int rg = 0; rg < 4; ++rg)
#pragma unroll
      for (int r = 0; r < 4; ++r) {
        float v = vals[i][rg][r] + bv;
        if (MODE == 2) v = fmaxf(v, 0.f);
        Ls[(rg * 16 + (quad << 2) + r) * LS_STRIDE + col] = f2bf(v);
      }
  }
  __syncthreads();
  lds_store_rows(Ls, (u16*)out, r0, M, w, lane);
}

// ---- fused offsets + attention-softmax GEMM: A = bf16(query + pos) ----
__global__ __launch_bounds__(256, 3) void offaw_gemm_kernel(
    const float* __restrict__ query, const float* __restrict__ pos,
    const u16* __restrict__ Bt, const float* __restrict__ b_off,
    const float* __restrict__ b_attn, u16* __restrict__ offb,
    float* __restrict__ aw, int M) {
  __shared__ uint4 As[2176];
  const int tid = threadIdx.x;
  const int w = tid >> 6, lane = tid & 63, quad = lane >> 4, l16 = lane & 15;
  const int r0 = blockIdx.x * 64;
  stage_a_f32<1, 4>(As, query, pos, r0, M, tid);
  __syncthreads();
  i16x8 bfr[2][8];
  load_b(bfr[0], Bt, w, l16, quad);
  f32x4 vals[4][4];
#pragma unroll
  for (int i = 0; i < 6; ++i) {
    const int t = w + 4 * i;
    if (i + 1 < 6) load_b(bfr[(i + 1) & 1], Bt, w + 4 * (i + 1), l16, quad);
    if (i < 4) {
      tile_mfma(vals[i], As, bfr[i & 1], l16, quad);
    } else {
      f32x4 acc[4];
      tile_mfma(acc, As, bfr[i & 1], l16, quad);
      const int colc = (t - 16) * 16 + l16;
      const float bv = b_attn[colc];
#pragma unroll
      for (int rg = 0; rg < 4; ++rg)
#pragma unroll
        for (int r = 0; r < 4; ++r) {
          float v = acc[rg][r] + bv;
          float m = v;
#pragma unroll
          for (int o = 1; o < 16; o <<= 1) m = fmaxf(m, __shfl_xor(m, o));
          float e = __expf(v - m);
          float s = e;
#pragma unroll
          for (int o = 1; o < 16; o <<= 1) s += __shfl_xor(s, o);
          int row = r0 + rg * 16 + (quad << 2) + r;
          if (row < M) aw[row * 128 + colc] = e / s;
        }
    }
  }
  // ---- vectorized offb epilogue ----
  __syncthreads();
  u16* Ls = (u16*)As;
#pragma unroll
  for (int i = 0; i < 4; ++i) {
    const int col = (w + 4 * i) * 16 + l16;
    const float bv = b_off[col];
#pragma unroll
    for (int rg = 0; rg < 4; ++rg)
#pragma unroll
      for (int r = 0; r < 4; ++r)
        Ls[(rg * 16 + (quad << 2) + r) * LS_STRIDE + col] = f2bf(vals[i][rg][r] + bv);
  }
  __syncthreads();
  lds_store_rows(Ls, offb, r0, M, w, lane);
}

// ---- GEMM + residual + LayerNorm; cross-wave LN partials through LDS ----
template <int RBF, int OBF>
__global__ __launch_bounds__(256, 2) void gemm_ln_kernel(
    const u16* __restrict__ A, const u16* __restrict__ Bt,
    const float* __restrict__ bias, const void* __restrict__ residv,
    const float* __restrict__ g, const float* __restrict__ beta,
    void* __restrict__ outv, int M) {
  __shared__ uint4 As[2176];
  __shared__ float2 pnorm[256];  // [row][wave] partial {s, s2}
  const int tid = threadIdx.x;
  const int w = tid >> 6, lane = tid & 63, quad = lane >> 4, l16 = lane & 15;
  const int r0 = blockIdx.x * 64;
  stage_a_dma(As, A, r0, M, w, lane);
  __syncthreads();
  i16x8 bfr[2][8];
  load_b(bfr[0], Bt, w * 4, l16, quad);
  f32x4 vals[4][4];  // [tile][rg]
#pragma unroll
  for (int i = 0; i < 4; ++i) {
    const int t = w * 4 + i;
    if (i + 1 < 4) load_b(bfr[(i + 1) & 1], Bt, t + 1, l16, quad);
    tile_mfma(vals[i], As, bfr[i & 1], l16, quad);
  }
  // bias + residual + stats
  float s[16], s2[16];
#pragma unroll
  for (int k = 0; k < 16; ++k) { s[k] = 0.f; s2[k] = 0.f; }
#pragma unroll
  for (int i = 0; i < 4; ++i) {
    const int col = (w * 4 + i) * 16 + l16;
    const float bv = bias[col];
#pragma unroll
    for (int rg = 0; rg < 4; ++rg)
#pragma unroll
      for (int r = 0; r < 4; ++r) {
        int row = r0 + rg * 16 + (quad << 2) + r;
        float rv = 0.f;
        if (row < M) rv = RBF ? bf2f(((const u16*)residv)[row * 256 + col])
                              : ((const float*)residv)[row * 256 + col];
        float v = vals[i][rg][r] + bv + rv;
        vals[i][rg][r] = v;
        s[rg * 4 + r] += v; s2[rg * 4 + r] += v * v;
      }
  }
  // reduce over the 16 l16 lanes (this wave's 64 cols), publish partials
#pragma unroll
  for (int k = 0; k < 16; ++k)
#pragma unroll
    for (int o = 1; o < 16; o <<= 1) {
      s[k] += __shfl_xor(s[k], o);
      s2[k] += __shfl_xor(s2[k], o);
    }
  if (l16 == 0) {
#pragma unroll
    for (int rg = 0; rg < 4; ++rg)
#pragma unroll
      for (int r = 0; r < 4; ++r) {
        int lrow = rg * 16 + (quad << 2) + r;
        pnorm[lrow * 4 + w] = make_float2(s[rg * 4 + r], s2[rg * 4 + r]);
      }
  }
  __syncthreads();
  // combine 4 wave-partials, normalize, store
  if constexpr (OBF) {
    u16* Ls = (u16*)As;  // As reads all completed before the pnorm barrier
#pragma unroll
    for (int rg = 0; rg < 4; ++rg)
#pragma unroll
      for (int r = 0; r < 4; ++r) {
        int lrow = rg * 16 + (quad << 2) + r;
        float4 p01 = ((const float4*)pnorm)[lrow * 2];
        float4 p23 = ((const float4*)pnorm)[lrow * 2 + 1];
        float ss = p01.x + p01.z + p23.x + p23.z;
        float qq = p01.y + p01.w + p23.y + p23.w;
        float mean = ss * (1.f / 256.f);
        float var = qq * (1.f / 256.f) - mean * mean;
        float inv = rsqrtf(var + 1e-5f);
#pragma unroll
        for (int i = 0; i < 4; ++i) {
          const int col = (w * 4 + i) * 16 + l16;
          float o = (vals[i][rg][r] - mean) * inv * g[col] + beta[col];
          Ls[lrow * LS_STRIDE + col] = f2bf(o);
        }
      }
    __syncthreads();
    lds_store_rows(Ls, (u16*)outv, r0, M, w, lane);
  } else {
#pragma unroll
    for (int rg = 0; rg < 4; ++rg)
#pragma unroll
      for (int r = 0; r < 4; ++r) {
        int lrow = rg * 16 + (quad << 2) + r;
        float4 p01 = ((const float4*)pnorm)[lrow * 2];
        float4 p23 = ((const float4*)pnorm)[lrow * 2 + 1];
        float ss = p01.x + p01.z + p23.x + p23.z;
        float qq = p01.y + p01.w + p23.y + p23.w;
        float mean = ss * (1.f / 256.f);
        float var = qq * (1.f / 256.f) - mean * mean;
        float inv = rsqrtf(var + 1e-5f);
        int row = r0 + lrow;
        if (row < M) {
#pragma unroll
          for (int i = 0; i < 4; ++i) {
            const int col = (w * 4 + i) * 16 + l16;
            float o = (vals[i][rg][r] - mean) * inv * g[col] + beta[col];
            ((float*)outv)[row * 256 + col] = o;
          }
        }
      }
  }
}

// ---- fused prep + deformable sampling: one block = 2 queries ----
// Inner loop: v_perm pairs the two x-taps' matching elements; v_dot2_f32_bf16
// does {v0,v1}·{w0,w1}+acc in one op (weights already packed bf16 in r.z/r.w).
__global__ __launch_bounds__(256) void sampler_kernel(
    const float* __restrict__ refp, const u16* __restrict__ offb,
    const float* __restrict__ aw, const u16* __restrict__ value,
    u32* __restrict__ accv) {
  __shared__ uint4 rec[272];
  const int t = threadIdx.x;
  const int b = blockIdx.x;
  {
    const int qs = t >> 7, j = t & 127;
    const int i = b * 2 + qs;
    const int h = j >> 4, lp = j & 15, l = lp >> 2;
    const int Wl = (l == 0) ? 180 : (l == 1) ? 90 : (l == 2) ? 45 : 23;
    const int st = (l == 0) ? 0 : (l == 1) ? 32400 : (l == 2) ? 40500 : 42525;
    const float wj = aw[i * 128 + j];
    const u32 o2 = *(const u32*)(offb + i * 256 + h * 32 + lp * 2);
    const float ox = bf2f((u16)(o2 & 0xffffu)), oy = bf2f((u16)(o2 >> 16));
    const float rx = refp[i * 8 + l * 2], ry = refp[i * 8 + l * 2 + 1];
    float x = rx * (float)Wl + ox - 0.5f;
    float y = ry * (float)Wl + oy - 0.5f;
    float x0f = floorf(x), y0f = floorf(y);
    float fx = x - x0f, fy = y - y0f;
    int x0 = (int)x0f, y0 = (int)y0f;
    bool vx0 = (x0 >= 0) & (x0 < Wl), vx1 = (x0 + 1 >= 0) & (x0 + 1 < Wl);
    bool vy0 = (y0 >= 0) & (y0 < Wl), vy1 = (y0 + 1 >= 0) & (y0 + 1 < Wl);
    int x0c = min(max(x0, 0), Wl - 1), x1c = min(max(x0 + 1, 0), Wl - 1);
    int y0c = min(max(y0, 0), Wl - 1), y1c = min(max(y0 + 1, 0), Wl - 1);
    float w00 = (vx0 & vy0) ? wj * (1.f - fx) * (1.f - fy) : 0.f;
    float w01 = (vx1 & vy0) ? wj * fx * (1.f - fy) : 0.f;
    float w10 = (vx0 & vy1) ? wj * (1.f - fx) * fy : 0.f;
    float w11 = (vx1 & vy1) ? wj * fx * fy : 0.f;
    uint4 r;
    r.x = (u32)((st + y0c * Wl + x0c) * 512 + h * 64) | (u32)(x1c - x0c);
    r.y = (u32)(y1c - y0c) * (u32)(Wl * 512);
    r.z = (u32)f2bf(w00) | ((u32)f2bf(w01) << 16);
    r.w = (u32)f2bf(w10) | ((u32)f2bf(w11) << 16);
    rec[qs * 136 + h * 17 + lp] = r;
  }
  __syncthreads();
  const int qs = t >> 7, j = t & 127;
  const int h = j >> 4, dp = j & 15;
  const char* vb = (const char*)value;
  float a0 = 0.f, a1 = 0.f;
  const int rbase = qs * 136 + h * 17;
  const u32 dp4 = (u32)(dp * 4);
#pragma unroll
  for (int p = 0; p < 16; ++p) {
    uint4 r = rec[rbase + p];
    u32 base = (r.x & 0xFFFFFFFEu) + dp4;
    u32 dxo = (r.x & 1u) << 9;
    u32 dyo = r.y;
    u32 p00 = *(const u32*)(vb + base);
    u32 p01 = *(const u32*)(vb + base + dxo);
    u32 p10 = *(const u32*)(vb + base + dyo);
    u32 p11 = *(const u32*)(vb + base + dyo + dxo);
    // lo halves (element d0): {p00.lo, p01.lo}; hi halves (element d1)
    a0 = dot2bf(__builtin_amdgcn_perm(p01, p00, 0x05040100u), r.z, a0);
    a1 = dot2bf(__builtin_amdgcn_perm(p01, p00, 0x07060302u), r.z, a1);
    a0 = dot2bf(__builtin_amdgcn_perm(p11, p10, 0x05040100u), r.w, a0);
    a1 = dot2bf(__builtin_amdgcn_perm(p11, p10, 0x07060302u), r.w, a1);
  }
  u32 pk = (u32)f2bf(a0) | ((u32)f2bf(a1) << 16);
  accv[(b * 2 + qs) * 128 + j] = pk;
}

extern "C" void kernel_launch(void* const* d_in, const int* in_sizes, int n_in,
                              void* d_out, int out_size, void* d_ws, size_t ws_size,
                              hipStream_t stream) {
  const float* query  = (const float*)d_in[0];
  const float* refp   = (const float*)d_in[1];
  const float* pos    = (const float*)d_in[2];
  const float* w_off  = (const float*)d_in[5];
  const float* b_off  = (const float*)d_in[6];
  const float* w_attn = (const float*)d_in[7];
  const float* b_attn = (const float*)d_in[8];
  const float* w_val  = (const float*)d_in[9];
  const float* b_val  = (const float*)d_in[10];
  const float* w_out  = (const float*)d_in[11];
  const float* b_out  = (const float*)d_in[12];
  const float* g1     = (const float*)d_in[13];
  const float* beta1  = (const float*)d_in[14];
  const float* w1     = (const float*)d_in[15];
  const float* b1     = (const float*)d_in[16];
  const float* w2     = (const float*)d_in[17];
  const float* b2     = (const float*)d_in[18];
  const float* g2     = (const float*)d_in[19];
  const float* beta2  = (const float*)d_in[20];

  char* ws = (char*)d_ws;
  u16*   wT    = (u16*)(ws + 0);            //   720,896, live whole launch
  u16*   value = (u16*)(ws + 720896);       // 22,043,648  dead after sampler
  u16*   offb  = (u16*)(ws + 22764544);     // 22,043,648  dead after sampler
  float* aw    = (float*)(ws + 44808192);   // 22,043,648  dead after sampler
  u16*   accb  = (u16*)(ws + 66851840);     // 22,043,648  dead after out-proj
  u16*   xb    = (u16*)(ws + 720896);       // over value (dead)
  u16*   hb    = (u16*)(ws + 22764544);     // over offb (dead)

  u16* woffT  = wT;                // 256 rows; wattnT contiguous after (384-row B)
  u16* wvalT  = wT + 98304;
  u16* woutT  = wT + 163840;
  u16* w1T    = wT + 229376;
  u16* w2T    = wT + 294912;

  transpose_all_kernel<<<1408, 256, 0, stream>>>(w_off, w_attn, w_val, w_out, w1, w2, wT);

  const int gm = (LQ + 63) / 64;  // 673
  gemm_kernel<0, 1><<<gm, 256, 0, stream>>>(query, wvalT, b_val, value, LQ);
  offaw_gemm_kernel<<<gm, 256, 0, stream>>>(query, pos, woffT, b_off, b_attn, offb, aw, LQ);
  sampler_kernel<<<LQ / 2, 256, 0, stream>>>(refp, offb, aw, value, (u32*)accb);
  gemm_ln_kernel<0, 1><<<gm, 256, 0, stream>>>(accb, woutT, b_out, query, g1, beta1, xb, LQ);
  gemm_kernel<2, 2><<<gm, 256, 0, stream>>>(xb, w1T, b1, hb, LQ);
  gemm_ln_kernel<1, 0><<<gm, 256, 0, stream>>>(hb, w2T, b2, xb, g2, beta2, d_out, LQ);
}

// Round 3
// 407.513 us; speedup vs baseline: 1.1378x; 1.0288x over previous
//
#include <hip/hip_runtime.h>

typedef unsigned short u16;
typedef unsigned int u32;
typedef float f32x4 __attribute__((ext_vector_type(4)));
typedef short i16x8 __attribute__((ext_vector_type(8)));
typedef __bf16 bf16x8_t __attribute__((ext_vector_type(8)));

#define LQ 43054

__device__ __forceinline__ float bf2f(u16 u) {
  union { u32 i; float f; } v; v.i = ((u32)u) << 16; return v.f;
}
__device__ __forceinline__ u16 f2bf(float f) {
  u32 i = __float_as_uint(f);
  return (u16)((i + 0x7FFFu + ((i >> 16) & 1u)) >> 16);
}

// D = S0.lo*S1.lo + S0.hi*S1.hi + S2  (bf16 pairs, f32 accumulate)
__device__ __forceinline__ float dot2bf(u32 v, u32 w, float c) {
  float d;
  asm("v_dot2_f32_bf16 %0, %1, %2, %3" : "=v"(d) : "v"(v), "v"(w), "v"(c));
  return d;
}

// ---- MFMA wrapper robust to builtin operand type (V8 short vs V8 __bf16) ----
template <typename T>
__device__ __forceinline__ auto mfma_try(T a, T b, f32x4 c, int)
    -> decltype(__builtin_amdgcn_mfma_f32_16x16x32_bf16(a, b, c, 0, 0, 0)) {
  return __builtin_amdgcn_mfma_f32_16x16x32_bf16(a, b, c, 0, 0, 0);
}
template <typename T>
__device__ __forceinline__ f32x4 mfma_try(T a, T b, f32x4 c, long) {
  return __builtin_amdgcn_mfma_f32_16x16x32_bf16(
      __builtin_bit_cast(bf16x8_t, a), __builtin_bit_cast(bf16x8_t, b), c, 0, 0, 0);
}
__device__ __forceinline__ f32x4 mfma_bf16(i16x8 a, i16x8 b, f32x4 c) {
  return mfma_try(a, b, c, 0);
}

// ---- all 6 weight transposes in one kernel: f32 (256 x N) -> bf16 (N x 256) ----
__global__ void transpose_all_kernel(
    const float* __restrict__ w_off, const float* __restrict__ w_attn,
    const float* __restrict__ w_val, const float* __restrict__ w_out,
    const float* __restrict__ w1, const float* __restrict__ w2,
    u16* __restrict__ wT) {
  int b = blockIdx.x;
  const float* src; u16* dst; int N; int col;
  if (b < 256)       { src = w_off;  dst = wT;          N = 256; col = b; }
  else if (b < 384)  { src = w_attn; dst = wT + 65536;  N = 128; col = b - 256; }
  else if (b < 640)  { src = w_val;  dst = wT + 98304;  N = 256; col = b - 384; }
  else if (b < 896)  { src = w_out;  dst = wT + 163840; N = 256; col = b - 640; }
  else if (b < 1152) { src = w1;     dst = wT + 229376; N = 256; col = b - 896; }
  else               { src = w2;     dst = wT + 294912; N = 256; col = b - 1152; }
  dst[col * 256 + threadIdx.x] = f2bf(src[threadIdx.x * N + col]);
}

// ================= shared helpers ==========================================
// DMA staging for bf16 A: linear LDS dest, XOR-swizzle applied to the per-lane
// GLOBAL source column (involution; reads recover A[row][col] exactly).
// Tail rows are clamped to M-1 (finite garbage; never stored).
__device__ __forceinline__ void stage_a_dma(uint4* As, const u16* A, int r0, int M,
                                            int w, int lane) {
#pragma unroll
  for (int jj = 0; jj < 8; ++jj) {
    int row = w * 16 + jj * 2 + (lane >> 5);
    int gr = min(r0 + row, M - 1);
    int c = lane & 31;
    const uint4* gp = (const uint4*)A + (size_t)gr * 32 + (c ^ (row & 7));
    __builtin_amdgcn_global_load_lds(
        (const __attribute__((address_space(1))) void*)gp,
        (__attribute__((address_space(3))) void*)(As + (w * 16 + jj * 2) * 32),
        16, 0, 0);
  }
}
// f32 staging, phased: issue IT loads, then convert+write
template <int ADD, int PH>
__device__ __forceinline__ void stage_a_f32(uint4* As, const float* A, const float* A2,
                                            int r0, int M, int tid) {
  constexpr int IT = 16 / PH;
#pragma unroll
  for (int h = 0; h < PH; ++h) {
    float4 va[IT];
    float4 vp[ADD ? IT : 1];
#pragma unroll
    for (int it = 0; it < IT; ++it) {
      int e = tid + (h * IT + it) * 256;
      int gr = min(r0 + (e >> 6), M - 1);
      int idx = gr * 64 + (e & 63);
      va[it] = ((const float4*)A)[idx];
      if constexpr (ADD) vp[it] = ((const float4*)A2)[idx];
    }
#pragma unroll
    for (int it = 0; it < IT; ++it) {
      int e = tid + (h * IT + it) * 256;
      int row = e >> 6, c4 = e & 63;
      float4 v = va[it];
      if constexpr (ADD) {
        v.x += vp[it].x; v.y += vp[it].y; v.z += vp[it].z; v.w += vp[it].w;
      }
      uint2 pk;
      pk.x = (u32)f2bf(v.x) | ((u32)f2bf(v.y) << 16);
      pk.y = (u32)f2bf(v.z) | ((u32)f2bf(v.w) << 16);
      int c = c4 >> 1, hf = c4 & 1;
      ((uint2*)As)[((row * 32 + (c ^ (row & 7))) << 1) | hf] = pk;
    }
  }
}
// load one 16-col B tile's 8 K-fragments into registers
__device__ __forceinline__ void load_b(i16x8* f, const u16* Bt, int t, int l16, int quad) {
  const uint4* bp = (const uint4*)Bt + (t * 16 + l16) * 32 + quad;
#pragma unroll
  for (int kk = 0; kk < 8; ++kk) f[kk] = __builtin_bit_cast(i16x8, bp[kk << 2]);
}
// 32 MFMAs of one tile over all 4 row-groups, A from LDS
__device__ __forceinline__ void tile_mfma(f32x4* acc, const uint4* As,
                                          const i16x8* bfr, int l16, int quad) {
#pragma unroll
  for (int rg = 0; rg < 4; ++rg) {
    int arow = rg * 16 + l16;
    f32x4 a = {0.f, 0.f, 0.f, 0.f};
#pragma unroll
    for (int kk = 0; kk < 8; ++kk) {
      i16x8 afr = __builtin_bit_cast(i16x8, As[arow * 32 + (((kk << 2) + quad) ^ (arow & 7))]);
      a = mfma_bf16(afr, bfr[kk], a);
    }
    acc[rg] = a;
  }
}

// u16 index into a GEMM-A swizzled LDS tile for element (row, col)
__device__ __forceinline__ int swz_u16(int row, int col) {
  return row * 256 + ((((col >> 3) ^ (row & 7)) << 3) | (col & 7));
}

// LDS output staging: u16 rows with stride 264 (528 B: 16B-aligned, bank-skewed).
#define LS_STRIDE 264
// vectorized store: each iteration a wave writes 2 complete 512-B rows
__device__ __forceinline__ void lds_store_rows(const u16* Ls, u16* out,
                                               int r0, int M, int w, int lane) {
#pragma unroll
  for (int it = 0; it < 8; ++it) {
    int lrow = w * 16 + it * 2 + (lane >> 5);
    int grow = r0 + lrow;
    int chunk = lane & 31;
    if (grow < M) {
      *(uint4*)(out + (size_t)grow * 256 + chunk * 8) =
          *(const uint4*)(Ls + lrow * LS_STRIDE + chunk * 8);
    }
  }
}

// ---- generic GEMM: wave owns 4 col-tiles, sweeps all 64 rows ----
// AIN: 0 = A f32, 2 = A bf16 (DMA).  MODE: 1 = bf16, 2 = relu+bf16.
template <int AIN, int MODE>
__global__ __launch_bounds__(256, 3) void gemm_kernel(
    const void* __restrict__ Av, const u16* __restrict__ Bt,
    const float* __restrict__ bias, void* __restrict__ out, int M) {
  __shared__ uint4 As[2176];
  const int tid = threadIdx.x;
  const int w = tid >> 6, lane = tid & 63, quad = lane >> 4, l16 = lane & 15;
  const int r0 = blockIdx.x * 64;
  if constexpr (AIN == 2) stage_a_dma(As, (const u16*)Av, r0, M, w, lane);
  else                    stage_a_f32<0, 2>(As, (const float*)Av, nullptr, r0, M, tid);
  __syncthreads();
  i16x8 bfr[2][8];
  load_b(bfr[0], Bt, w * 4, l16, quad);
  f32x4 vals[4][4];
#pragma unroll
  for (int i = 0; i < 4; ++i) {
    const int t = w * 4 + i;
    if (i + 1 < 4) load_b(bfr[(i + 1) & 1], Bt, t + 1, l16, quad);
    tile_mfma(vals[i], As, bfr[i & 1], l16, quad);
  }
  // ---- vectorized epilogue: regs -> LDS (transpose) -> dwordx4 stores ----
  __syncthreads();  // all waves done reading As
  u16* Ls = (u16*)As;
#pragma unroll
  for (int i = 0; i < 4; ++i) {
    const int col = (w * 4 + i) * 16 + l16;
    const float bv = bias[col];
#pragma unroll
    for (int rg = 0; rg < 4; ++rg)
#pragma unroll
      for (int r = 0; r < 4; ++r) {
        float v = vals[i][rg][r] + bv;
        if (MODE == 2) v = fmaxf(v, 0.f);
        Ls[(rg * 16 + (quad << 2) + r) * LS_STRIDE + col] = f2bf(v);
      }
  }
  __syncthreads();
  lds_store_rows(Ls, (u16*)out, r0, M, w, lane);
}

// ---- fused offsets + attention-softmax GEMM: A = bf16(query + pos) ----
__global__ __launch_bounds__(256, 3) void offaw_gemm_kernel(
    const float* __restrict__ query, const float* __restrict__ pos,
    const u16* __restrict__ Bt, const float* __restrict__ b_off,
    const float* __restrict__ b_attn, u16* __restrict__ offb,
    float* __restrict__ aw, int M) {
  __shared__ uint4 As[2176];
  const int tid = threadIdx.x;
  const int w = tid >> 6, lane = tid & 63, quad = lane >> 4, l16 = lane & 15;
  const int r0 = blockIdx.x * 64;
  stage_a_f32<1, 4>(As, query, pos, r0, M, tid);
  __syncthreads();
  i16x8 bfr[2][8];
  load_b(bfr[0], Bt, w, l16, quad);
  f32x4 vals[4][4];
#pragma unroll
  for (int i = 0; i < 6; ++i) {
    const int t = w + 4 * i;
    if (i + 1 < 6) load_b(bfr[(i + 1) & 1], Bt, w + 4 * (i + 1), l16, quad);
    if (i < 4) {
      tile_mfma(vals[i], As, bfr[i & 1], l16, quad);
    } else {
      f32x4 acc[4];
      tile_mfma(acc, As, bfr[i & 1], l16, quad);
      const int colc = (t - 16) * 16 + l16;
      const float bv = b_attn[colc];
#pragma unroll
      for (int rg = 0; rg < 4; ++rg)
#pragma unroll
        for (int r = 0; r < 4; ++r) {
          float v = acc[rg][r] + bv;
          float m = v;
#pragma unroll
          for (int o = 1; o < 16; o <<= 1) m = fmaxf(m, __shfl_xor(m, o));
          float e = __expf(v - m);
          float s = e;
#pragma unroll
          for (int o = 1; o < 16; o <<= 1) s += __shfl_xor(s, o);
          int row = r0 + rg * 16 + (quad << 2) + r;
          if (row < M) aw[row * 128 + colc] = e / s;
        }
    }
  }
  // ---- vectorized offb epilogue ----
  __syncthreads();
  u16* Ls = (u16*)As;
#pragma unroll
  for (int i = 0; i < 4; ++i) {
    const int col = (w + 4 * i) * 16 + l16;
    const float bv = b_off[col];
#pragma unroll
    for (int rg = 0; rg < 4; ++rg)
#pragma unroll
      for (int r = 0; r < 4; ++r)
        Ls[(rg * 16 + (quad << 2) + r) * LS_STRIDE + col] = f2bf(vals[i][rg][r] + bv);
  }
  __syncthreads();
  lds_store_rows(Ls, offb, r0, M, w, lane);
}

// ---- fused tail: out-proj -> +query -> LN1 -> FFN1(relu) -> FFN2 -> +x -> LN2 ----
// x and h stay in LDS (GEMM-A swizzled layout); h reuses the dead accb stage buffer.
// Bit-identical to the previous 3-kernel chain (same bf16 intermediates).
__global__ __launch_bounds__(256, 2) void tail_fused_kernel(
    const u16* __restrict__ accb, const u16* __restrict__ woutT,
    const float* __restrict__ b_out, const float* __restrict__ query,
    const float* __restrict__ g1, const float* __restrict__ beta1,
    const u16* __restrict__ w1T, const float* __restrict__ b1,
    const u16* __restrict__ w2T, const float* __restrict__ b2,
    const float* __restrict__ g2, const float* __restrict__ beta2,
    float* __restrict__ out, int M) {
  __shared__ uint4 As[2048];   // accb staged; later reused for h
  __shared__ uint4 Xs[2048];   // LN1 output x (bf16, GEMM-A swizzled)
  __shared__ float2 pnorm[256];
  const int tid = threadIdx.x;
  const int w = tid >> 6, lane = tid & 63, quad = lane >> 4, l16 = lane & 15;
  const int r0 = blockIdx.x * 64;
  stage_a_dma(As, accb, r0, M, w, lane);
  __syncthreads();
  i16x8 bfr[2][8];
  f32x4 vals[4][4];
  float s[16], s2[16];

  // ---------- stage 1: out-proj GEMM ----------
  load_b(bfr[0], woutT, w * 4, l16, quad);
#pragma unroll
  for (int i = 0; i < 4; ++i) {
    if (i + 1 < 4) load_b(bfr[(i + 1) & 1], woutT, w * 4 + i + 1, l16, quad);
    tile_mfma(vals[i], As, bfr[i & 1], l16, quad);
  }
#pragma unroll
  for (int k = 0; k < 16; ++k) { s[k] = 0.f; s2[k] = 0.f; }
#pragma unroll
  for (int i = 0; i < 4; ++i) {
    const int col = (w * 4 + i) * 16 + l16;
    const float bv = b_out[col];
#pragma unroll
    for (int rg = 0; rg < 4; ++rg)
#pragma unroll
      for (int r = 0; r < 4; ++r) {
        int row = r0 + rg * 16 + (quad << 2) + r;
        float rv = (row < M) ? query[row * 256 + col] : 0.f;
        float v = vals[i][rg][r] + bv + rv;
        vals[i][rg][r] = v;
        s[rg * 4 + r] += v; s2[rg * 4 + r] += v * v;
      }
  }
#pragma unroll
  for (int k = 0; k < 16; ++k)
#pragma unroll
    for (int o = 1; o < 16; o <<= 1) {
      s[k] += __shfl_xor(s[k], o);
      s2[k] += __shfl_xor(s2[k], o);
    }
  if (l16 == 0) {
#pragma unroll
    for (int rg = 0; rg < 4; ++rg)
#pragma unroll
      for (int r = 0; r < 4; ++r)
        pnorm[(rg * 16 + (quad << 2) + r) * 4 + w] = make_float2(s[rg * 4 + r], s2[rg * 4 + r]);
  }
  __syncthreads();
  // LN1 normalize -> Xs (bf16, swizzled A layout)
  u16* Xu = (u16*)Xs;
#pragma unroll
  for (int rg = 0; rg < 4; ++rg)
#pragma unroll
    for (int r = 0; r < 4; ++r) {
      int lrow = rg * 16 + (quad << 2) + r;
      float4 p01 = ((const float4*)pnorm)[lrow * 2];
      float4 p23 = ((const float4*)pnorm)[lrow * 2 + 1];
      float ss = p01.x + p01.z + p23.x + p23.z;
      float qq = p01.y + p01.w + p23.y + p23.w;
      float mean = ss * (1.f / 256.f);
      float var = qq * (1.f / 256.f) - mean * mean;
      float inv = rsqrtf(var + 1e-5f);
#pragma unroll
      for (int i = 0; i < 4; ++i) {
        const int col = (w * 4 + i) * 16 + l16;
        float o = (vals[i][rg][r] - mean) * inv * g1[col] + beta1[col];
        Xu[swz_u16(lrow, col)] = f2bf(o);
      }
    }
  __syncthreads();  // Xs ready; As free

  // ---------- stage 2: FFN1 = relu(x @ w1 + b1) -> h into As ----------
  load_b(bfr[0], w1T, w * 4, l16, quad);
#pragma unroll
  for (int i = 0; i < 4; ++i) {
    if (i + 1 < 4) load_b(bfr[(i + 1) & 1], w1T, w * 4 + i + 1, l16, quad);
    tile_mfma(vals[i], Xs, bfr[i & 1], l16, quad);
  }
  u16* Hu = (u16*)As;
#pragma unroll
  for (int i = 0; i < 4; ++i) {
    const int col = (w * 4 + i) * 16 + l16;
    const float bv = b1[col];
#pragma unroll
    for (int rg = 0; rg < 4; ++rg)
#pragma unroll
      for (int r = 0; r < 4; ++r) {
        int lrow = rg * 16 + (quad << 2) + r;
        Hu[swz_u16(lrow, col)] = f2bf(fmaxf(vals[i][rg][r] + bv, 0.f));
      }
  }
  __syncthreads();  // h ready

  // ---------- stage 3: FFN2 = h @ w2 + b2 + x, LN2, store f32 ----------
  load_b(bfr[0], w2T, w * 4, l16, quad);
#pragma unroll
  for (int i = 0; i < 4; ++i) {
    if (i + 1 < 4) load_b(bfr[(i + 1) & 1], w2T, w * 4 + i + 1, l16, quad);
    tile_mfma(vals[i], As, bfr[i & 1], l16, quad);
  }
#pragma unroll
  for (int k = 0; k < 16; ++k) { s[k] = 0.f; s2[k] = 0.f; }
#pragma unroll
  for (int i = 0; i < 4; ++i) {
    const int col = (w * 4 + i) * 16 + l16;
    const float bv = b2[col];
#pragma unroll
    for (int rg = 0; rg < 4; ++rg)
#pragma unroll
      for (int r = 0; r < 4; ++r) {
        int lrow = rg * 16 + (quad << 2) + r;
        float xv = bf2f(Xu[swz_u16(lrow, col)]);
        float v = vals[i][rg][r] + bv + xv;
        vals[i][rg][r] = v;
        s[rg * 4 + r] += v; s2[rg * 4 + r] += v * v;
      }
  }
#pragma unroll
  for (int k = 0; k < 16; ++k)
#pragma unroll
    for (int o = 1; o < 16; o <<= 1) {
      s[k] += __shfl_xor(s[k], o);
      s2[k] += __shfl_xor(s2[k], o);
    }
  if (l16 == 0) {
#pragma unroll
    for (int rg = 0; rg < 4; ++rg)
#pragma unroll
      for (int r = 0; r < 4; ++r)
        pnorm[(rg * 16 + (quad << 2) + r) * 4 + w] = make_float2(s[rg * 4 + r], s2[rg * 4 + r]);
  }
  __syncthreads();
#pragma unroll
  for (int rg = 0; rg < 4; ++rg)
#pragma unroll
    for (int r = 0; r < 4; ++r) {
      int lrow = rg * 16 + (quad << 2) + r;
      float4 p01 = ((const float4*)pnorm)[lrow * 2];
      float4 p23 = ((const float4*)pnorm)[lrow * 2 + 1];
      float ss = p01.x + p01.z + p23.x + p23.z;
      float qq = p01.y + p01.w + p23.y + p23.w;
      float mean = ss * (1.f / 256.f);
      float var = qq * (1.f / 256.f) - mean * mean;
      float inv = rsqrtf(var + 1e-5f);
      int row = r0 + lrow;
      if (row < M) {
#pragma unroll
        for (int i = 0; i < 4; ++i) {
          const int col = (w * 4 + i) * 16 + l16;
          out[row * 256 + col] = (vals[i][rg][r] - mean) * inv * g2[col] + beta2[col];
        }
      }
    }
}

// ---- fused prep + deformable sampling: one block = 4 queries ----
// dwordx2 value loads (4 elems per tap-load), dot2 accumulate; chunked
// bijective XCD swizzle so spatially-adjacent queries share an XCD L2.
__global__ __launch_bounds__(256) void sampler_kernel(
    const float* __restrict__ refp, const u16* __restrict__ offb,
    const float* __restrict__ aw, const u16* __restrict__ value,
    u32* __restrict__ accv) {
  __shared__ uint4 rec[544];
  const int t = threadIdx.x;
  // bijective chunked XCD swizzle (m204 variant)
  const int nwg = gridDim.x;
  const int qd = nwg >> 3, rm = nwg & 7;
  const int xcd = blockIdx.x & 7, ii = blockIdx.x >> 3;
  const int b = (xcd < rm ? xcd * (qd + 1) : rm * (qd + 1) + (xcd - rm) * qd) + ii;
#pragma unroll
  for (int it = 0; it < 2; ++it) {
    const int sidx = t + it * 256;
    const int qs = sidx >> 7, j = sidx & 127;
    const int i = b * 4 + qs;
    if (i < LQ) {
      const int h = j >> 4, lp = j & 15, l = lp >> 2;
      const int Wl = (l == 0) ? 180 : (l == 1) ? 90 : (l == 2) ? 45 : 23;
      const int st = (l == 0) ? 0 : (l == 1) ? 32400 : (l == 2) ? 40500 : 42525;
      const float wj = aw[i * 128 + j];
      const u32 o2 = *(const u32*)(offb + i * 256 + h * 32 + lp * 2);
      const float ox = bf2f((u16)(o2 & 0xffffu)), oy = bf2f((u16)(o2 >> 16));
      const float rx = refp[i * 8 + l * 2], ry = refp[i * 8 + l * 2 + 1];
      float x = rx * (float)Wl + ox - 0.5f;
      float y = ry * (float)Wl + oy - 0.5f;
      float x0f = floorf(x), y0f = floorf(y);
      float fx = x - x0f, fy = y - y0f;
      int x0 = (int)x0f, y0 = (int)y0f;
      bool vx0 = (x0 >= 0) & (x0 < Wl), vx1 = (x0 + 1 >= 0) & (x0 + 1 < Wl);
      bool vy0 = (y0 >= 0) & (y0 < Wl), vy1 = (y0 + 1 >= 0) & (y0 + 1 < Wl);
      int x0c = min(max(x0, 0), Wl - 1), x1c = min(max(x0 + 1, 0), Wl - 1);
      int y0c = min(max(y0, 0), Wl - 1), y1c = min(max(y0 + 1, 0), Wl - 1);
      float w00 = (vx0 & vy0) ? wj * (1.f - fx) * (1.f - fy) : 0.f;
      float w01 = (vx1 & vy0) ? wj * fx * (1.f - fy) : 0.f;
      float w10 = (vx0 & vy1) ? wj * (1.f - fx) * fy : 0.f;
      float w11 = (vx1 & vy1) ? wj * fx * fy : 0.f;
      uint4 r;
      r.x = (u32)((st + y0c * Wl + x0c) * 512 + h * 64) | (u32)(x1c - x0c);
      r.y = (u32)(y1c - y0c) * (u32)(Wl * 512);
      r.z = (u32)f2bf(w00) | ((u32)f2bf(w01) << 16);
      r.w = (u32)f2bf(w10) | ((u32)f2bf(w11) << 16);
      rec[qs * 136 + h * 17 + lp] = r;
    }
  }
  __syncthreads();
  const int qs = t >> 6, j2 = t & 63;
  const int h = j2 >> 3, dp8 = j2 & 7;
  const int i = b * 4 + qs;
  if (i >= LQ) return;
  const char* vb = (const char*)value;
  float a0 = 0.f, a1 = 0.f, a2 = 0.f, a3 = 0.f;
  const int rbase = qs * 136 + h * 17;
  const u32 dpo = (u32)(dp8 * 8);
#pragma unroll
  for (int p = 0; p < 16; ++p) {
    uint4 r = rec[rbase + p];
    u32 base = (r.x & 0xFFFFFFFEu) + dpo;
    u32 dxo = (r.x & 1u) << 9;
    u32 dyo = r.y;
    uint2 p00 = *(const uint2*)(vb + base);
    uint2 p01 = *(const uint2*)(vb + base + dxo);
    uint2 p10 = *(const uint2*)(vb + base + dyo);
    uint2 p11 = *(const uint2*)(vb + base + dyo + dxo);
    a0 = dot2bf(__builtin_amdgcn_perm(p01.x, p00.x, 0x05040100u), r.z, a0);
    a1 = dot2bf(__builtin_amdgcn_perm(p01.x, p00.x, 0x07060302u), r.z, a1);
    a2 = dot2bf(__builtin_amdgcn_perm(p01.y, p00.y, 0x05040100u), r.z, a2);
    a3 = dot2bf(__builtin_amdgcn_perm(p01.y, p00.y, 0x07060302u), r.z, a3);
    a0 = dot2bf(__builtin_amdgcn_perm(p11.x, p10.x, 0x05040100u), r.w, a0);
    a1 = dot2bf(__builtin_amdgcn_perm(p11.x, p10.x, 0x07060302u), r.w, a1);
    a2 = dot2bf(__builtin_amdgcn_perm(p11.y, p10.y, 0x05040100u), r.w, a2);
    a3 = dot2bf(__builtin_amdgcn_perm(p11.y, p10.y, 0x07060302u), r.w, a3);
  }
  uint2 pk;
  pk.x = (u32)f2bf(a0) | ((u32)f2bf(a1) << 16);
  pk.y = (u32)f2bf(a2) | ((u32)f2bf(a3) << 16);
  ((uint2*)accv)[i * 64 + h * 8 + dp8] = pk;
}

extern "C" void kernel_launch(void* const* d_in, const int* in_sizes, int n_in,
                              void* d_out, int out_size, void* d_ws, size_t ws_size,
                              hipStream_t stream) {
  const float* query  = (const float*)d_in[0];
  const float* refp   = (const float*)d_in[1];
  const float* pos    = (const float*)d_in[2];
  const float* w_off  = (const float*)d_in[5];
  const float* b_off  = (const float*)d_in[6];
  const float* w_attn = (const float*)d_in[7];
  const float* b_attn = (const float*)d_in[8];
  const float* w_val  = (const float*)d_in[9];
  const float* b_val  = (const float*)d_in[10];
  const float* w_out  = (const float*)d_in[11];
  const float* b_out  = (const float*)d_in[12];
  const float* g1     = (const float*)d_in[13];
  const float* beta1  = (const float*)d_in[14];
  const float* w1     = (const float*)d_in[15];
  const float* b1     = (const float*)d_in[16];
  const float* w2     = (const float*)d_in[17];
  const float* b2     = (const float*)d_in[18];
  const float* g2     = (const float*)d_in[19];
  const float* beta2  = (const float*)d_in[20];

  char* ws = (char*)d_ws;
  u16*   wT    = (u16*)(ws + 0);            //   720,896, live whole launch
  u16*   value = (u16*)(ws + 720896);       // dead after sampler
  u16*   offb  = (u16*)(ws + 22764544);     // dead after sampler
  float* aw    = (float*)(ws + 44808192);   // dead after sampler
  u16*   accb  = (u16*)(ws + 66851840);     // dead after tail

  u16* woffT  = wT;                // 256 rows; wattnT contiguous after (384-row B)
  u16* wvalT  = wT + 98304;
  u16* woutT  = wT + 163840;
  u16* w1T    = wT + 229376;
  u16* w2T    = wT + 294912;

  transpose_all_kernel<<<1408, 256, 0, stream>>>(w_off, w_attn, w_val, w_out, w1, w2, wT);

  const int gm = (LQ + 63) / 64;  // 673
  gemm_kernel<0, 1><<<gm, 256, 0, stream>>>(query, wvalT, b_val, value, LQ);
  offaw_gemm_kernel<<<gm, 256, 0, stream>>>(query, pos, woffT, b_off, b_attn, offb, aw, LQ);
  const int sb = (LQ + 3) / 4;  // 10764
  sampler_kernel<<<sb, 256, 0, stream>>>(refp, offb, aw, value, (u32*)accb);
  tail_fused_kernel<<<gm, 256, 0, stream>>>(accb, woutT, b_out, query, g1, beta1,
                                            w1T, b1, w2T, b2, g2, beta2,
                                            (float*)d_out, LQ);
}

// Round 4
// 394.432 us; speedup vs baseline: 1.1755x; 1.0332x over previous
//
#include <hip/hip_runtime.h>

typedef unsigned short u16;
typedef unsigned int u32;
typedef float f32x4 __attribute__((ext_vector_type(4)));
typedef short i16x8 __attribute__((ext_vector_type(8)));
typedef __bf16 bf16x8_t __attribute__((ext_vector_type(8)));

#define LQ 43054

__device__ __forceinline__ float bf2f(u16 u) {
  union { u32 i; float f; } v; v.i = ((u32)u) << 16; return v.f;
}
__device__ __forceinline__ u16 f2bf(float f) {
  u32 i = __float_as_uint(f);
  return (u16)((i + 0x7FFFu + ((i >> 16) & 1u)) >> 16);
}

// D = S0.lo*S1.lo + S0.hi*S1.hi + S2  (bf16 pairs, f32 accumulate)
__device__ __forceinline__ float dot2bf(u32 v, u32 w, float c) {
  float d;
  asm("v_dot2_f32_bf16 %0, %1, %2, %3" : "=v"(d) : "v"(v), "v"(w), "v"(c));
  return d;
}

// ---- MFMA wrapper robust to builtin operand type (V8 short vs V8 __bf16) ----
template <typename T>
__device__ __forceinline__ auto mfma_try(T a, T b, f32x4 c, int)
    -> decltype(__builtin_amdgcn_mfma_f32_16x16x32_bf16(a, b, c, 0, 0, 0)) {
  return __builtin_amdgcn_mfma_f32_16x16x32_bf16(a, b, c, 0, 0, 0);
}
template <typename T>
__device__ __forceinline__ f32x4 mfma_try(T a, T b, f32x4 c, long) {
  return __builtin_amdgcn_mfma_f32_16x16x32_bf16(
      __builtin_bit_cast(bf16x8_t, a), __builtin_bit_cast(bf16x8_t, b), c, 0, 0, 0);
}
__device__ __forceinline__ f32x4 mfma_bf16(i16x8 a, i16x8 b, f32x4 c) {
  return mfma_try(a, b, c, 0);
}

// ---- all 6 weight transposes in one kernel: f32 (256 x N) -> bf16 (N x 256) ----
__global__ void transpose_all_kernel(
    const float* __restrict__ w_off, const float* __restrict__ w_attn,
    const float* __restrict__ w_val, const float* __restrict__ w_out,
    const float* __restrict__ w1, const float* __restrict__ w2,
    u16* __restrict__ wT) {
  int b = blockIdx.x;
  const float* src; u16* dst; int N; int col;
  if (b < 256)       { src = w_off;  dst = wT;          N = 256; col = b; }
  else if (b < 384)  { src = w_attn; dst = wT + 65536;  N = 128; col = b - 256; }
  else if (b < 640)  { src = w_val;  dst = wT + 98304;  N = 256; col = b - 384; }
  else if (b < 896)  { src = w_out;  dst = wT + 163840; N = 256; col = b - 640; }
  else if (b < 1152) { src = w1;     dst = wT + 229376; N = 256; col = b - 896; }
  else               { src = w2;     dst = wT + 294912; N = 256; col = b - 1152; }
  dst[col * 256 + threadIdx.x] = f2bf(src[threadIdx.x * N + col]);
}

// ================= shared helpers ==========================================
// DMA staging for bf16 A: linear LDS dest, XOR-swizzle applied to the per-lane
// GLOBAL source column (involution; reads recover A[row][col] exactly).
// Tail rows are clamped to M-1 (finite garbage; never stored).
__device__ __forceinline__ void stage_a_dma(uint4* As, const u16* A, int r0, int M,
                                            int w, int lane) {
#pragma unroll
  for (int jj = 0; jj < 8; ++jj) {
    int row = w * 16 + jj * 2 + (lane >> 5);
    int gr = min(r0 + row, M - 1);
    int c = lane & 31;
    const uint4* gp = (const uint4*)A + (size_t)gr * 32 + (c ^ (row & 7));
    __builtin_amdgcn_global_load_lds(
        (const __attribute__((address_space(1))) void*)gp,
        (__attribute__((address_space(3))) void*)(As + (w * 16 + jj * 2) * 32),
        16, 0, 0);
  }
}
// f32 staging, phased: issue IT loads, then convert+write
template <int ADD, int PH>
__device__ __forceinline__ void stage_a_f32(uint4* As, const float* A, const float* A2,
                                            int r0, int M, int tid) {
  constexpr int IT = 16 / PH;
#pragma unroll
  for (int h = 0; h < PH; ++h) {
    float4 va[IT];
    float4 vp[ADD ? IT : 1];
#pragma unroll
    for (int it = 0; it < IT; ++it) {
      int e = tid + (h * IT + it) * 256;
      int gr = min(r0 + (e >> 6), M - 1);
      int idx = gr * 64 + (e & 63);
      va[it] = ((const float4*)A)[idx];
      if constexpr (ADD) vp[it] = ((const float4*)A2)[idx];
    }
#pragma unroll
    for (int it = 0; it < IT; ++it) {
      int e = tid + (h * IT + it) * 256;
      int row = e >> 6, c4 = e & 63;
      float4 v = va[it];
      if constexpr (ADD) {
        v.x += vp[it].x; v.y += vp[it].y; v.z += vp[it].z; v.w += vp[it].w;
      }
      uint2 pk;
      pk.x = (u32)f2bf(v.x) | ((u32)f2bf(v.y) << 16);
      pk.y = (u32)f2bf(v.z) | ((u32)f2bf(v.w) << 16);
      int c = c4 >> 1, hf = c4 & 1;
      ((uint2*)As)[((row * 32 + (c ^ (row & 7))) << 1) | hf] = pk;
    }
  }
}
// load one 16-col B tile's 8 K-fragments into registers
__device__ __forceinline__ void load_b(i16x8* f, const u16* Bt, int t, int l16, int quad) {
  const uint4* bp = (const uint4*)Bt + (t * 16 + l16) * 32 + quad;
#pragma unroll
  for (int kk = 0; kk < 8; ++kk) f[kk] = __builtin_bit_cast(i16x8, bp[kk << 2]);
}
// 32 MFMAs of one tile over all 4 row-groups (64-row blocks)
__device__ __forceinline__ void tile_mfma(f32x4* acc, const uint4* As,
                                          const i16x8* bfr, int l16, int quad) {
#pragma unroll
  for (int rg = 0; rg < 4; ++rg) {
    int arow = rg * 16 + l16;
    f32x4 a = {0.f, 0.f, 0.f, 0.f};
#pragma unroll
    for (int kk = 0; kk < 8; ++kk) {
      i16x8 afr = __builtin_bit_cast(i16x8, As[arow * 32 + (((kk << 2) + quad) ^ (arow & 7))]);
      a = mfma_bf16(afr, bfr[kk], a);
    }
    acc[rg] = a;
  }
}
// 16 MFMAs of one tile over 2 row-groups (32-row blocks)
__device__ __forceinline__ void tile_mfma2(f32x4* acc, const uint4* As,
                                           const i16x8* bfr, int l16, int quad) {
#pragma unroll
  for (int rg = 0; rg < 2; ++rg) {
    int arow = rg * 16 + l16;
    f32x4 a = {0.f, 0.f, 0.f, 0.f};
#pragma unroll
    for (int kk = 0; kk < 8; ++kk) {
      i16x8 afr = __builtin_bit_cast(i16x8, As[arow * 32 + (((kk << 2) + quad) ^ (arow & 7))]);
      a = mfma_bf16(afr, bfr[kk], a);
    }
    acc[rg] = a;
  }
}

// u16 index into a GEMM-A swizzled LDS tile for element (row, col)
__device__ __forceinline__ int swz_u16(int row, int col) {
  return row * 256 + ((((col >> 3) ^ (row & 7)) << 3) | (col & 7));
}

// LDS output staging: u16 rows with stride 264 (528 B: 16B-aligned, bank-skewed).
#define LS_STRIDE 264
// vectorized store: each iteration a wave writes 2 complete 512-B rows
__device__ __forceinline__ void lds_store_rows(const u16* Ls, u16* out,
                                               int r0, int M, int w, int lane) {
#pragma unroll
  for (int it = 0; it < 8; ++it) {
    int lrow = w * 16 + it * 2 + (lane >> 5);
    int grow = r0 + lrow;
    int chunk = lane & 31;
    if (grow < M) {
      *(uint4*)(out + (size_t)grow * 256 + chunk * 8) =
          *(const uint4*)(Ls + lrow * LS_STRIDE + chunk * 8);
    }
  }
}

// ---- generic GEMM: wave owns 4 col-tiles, sweeps all 64 rows ----
// AIN: 0 = A f32, 2 = A bf16 (DMA).  MODE: 1 = bf16, 2 = relu+bf16.
template <int AIN, int MODE>
__global__ __launch_bounds__(256, 3) void gemm_kernel(
    const void* __restrict__ Av, const u16* __restrict__ Bt,
    const float* __restrict__ bias, void* __restrict__ out, int M) {
  __shared__ uint4 As[2176];
  const int tid = threadIdx.x;
  const int w = tid >> 6, lane = tid & 63, quad = lane >> 4, l16 = lane & 15;
  const int r0 = blockIdx.x * 64;
  if constexpr (AIN == 2) stage_a_dma(As, (const u16*)Av, r0, M, w, lane);
  else                    stage_a_f32<0, 2>(As, (const float*)Av, nullptr, r0, M, tid);
  __syncthreads();
  i16x8 bfr[2][8];
  load_b(bfr[0], Bt, w * 4, l16, quad);
  f32x4 vals[4][4];
#pragma unroll
  for (int i = 0; i < 4; ++i) {
    const int t = w * 4 + i;
    if (i + 1 < 4) load_b(bfr[(i + 1) & 1], Bt, t + 1, l16, quad);
    tile_mfma(vals[i], As, bfr[i & 1], l16, quad);
  }
  // ---- vectorized epilogue: regs -> LDS (transpose) -> dwordx4 stores ----
  __syncthreads();  // all waves done reading As
  u16* Ls = (u16*)As;
#pragma unroll
  for (int i = 0; i < 4; ++i) {
    const int col = (w * 4 + i) * 16 + l16;
    const float bv = bias[col];
#pragma unroll
    for (int rg = 0; rg < 4; ++rg)
#pragma unroll
      for (int r = 0; r < 4; ++r) {
        float v = vals[i][rg][r] + bv;
        if (MODE == 2) v = fmaxf(v, 0.f);
        Ls[(rg * 16 + (quad << 2) + r) * LS_STRIDE + col] = f2bf(v);
      }
  }
  __syncthreads();
  lds_store_rows(Ls, (u16*)out, r0, M, w, lane);
}

// ---- fused offsets + attention-softmax GEMM: A = bf16(query + pos) ----
__global__ __launch_bounds__(256, 3) void offaw_gemm_kernel(
    const float* __restrict__ query, const float* __restrict__ pos,
    const u16* __restrict__ Bt, const float* __restrict__ b_off,
    const float* __restrict__ b_attn, u16* __restrict__ offb,
    float* __restrict__ aw, int M) {
  __shared__ uint4 As[2176];
  const int tid = threadIdx.x;
  const int w = tid >> 6, lane = tid & 63, quad = lane >> 4, l16 = lane & 15;
  const int r0 = blockIdx.x * 64;
  stage_a_f32<1, 4>(As, query, pos, r0, M, tid);
  __syncthreads();
  i16x8 bfr[2][8];
  load_b(bfr[0], Bt, w, l16, quad);
  f32x4 vals[4][4];
#pragma unroll
  for (int i = 0; i < 6; ++i) {
    const int t = w + 4 * i;
    if (i + 1 < 6) load_b(bfr[(i + 1) & 1], Bt, w + 4 * (i + 1), l16, quad);
    if (i < 4) {
      tile_mfma(vals[i], As, bfr[i & 1], l16, quad);
    } else {
      f32x4 acc[4];
      tile_mfma(acc, As, bfr[i & 1], l16, quad);
      const int colc = (t - 16) * 16 + l16;
      const float bv = b_attn[colc];
#pragma unroll
      for (int rg = 0; rg < 4; ++rg)
#pragma unroll
        for (int r = 0; r < 4; ++r) {
          float v = acc[rg][r] + bv;
          float m = v;
#pragma unroll
          for (int o = 1; o < 16; o <<= 1) m = fmaxf(m, __shfl_xor(m, o));
          float e = __expf(v - m);
          float s = e;
#pragma unroll
          for (int o = 1; o < 16; o <<= 1) s += __shfl_xor(s, o);
          int row = r0 + rg * 16 + (quad << 2) + r;
          if (row < M) aw[row * 128 + colc] = e / s;
        }
    }
  }
  // ---- vectorized offb epilogue ----
  __syncthreads();
  u16* Ls = (u16*)As;
#pragma unroll
  for (int i = 0; i < 4; ++i) {
    const int col = (w + 4 * i) * 16 + l16;
    const float bv = b_off[col];
#pragma unroll
    for (int rg = 0; rg < 4; ++rg)
#pragma unroll
      for (int r = 0; r < 4; ++r)
        Ls[(rg * 16 + (quad << 2) + r) * LS_STRIDE + col] = f2bf(vals[i][rg][r] + bv);
  }
  __syncthreads();
  lds_store_rows(Ls, offb, r0, M, w, lane);
}

// ---- fused tail: out-proj -> +query -> LN1 -> FFN1(relu) -> FFN2 -> +x -> LN2 ----
// 32 rows/block: LDS 33.8 KB -> 4 blocks/CU (vs 2 at 64 rows); VGPR <=128 for
// __launch_bounds__(256,4). x and h in LDS; final f32 out staged through LDS in
// two 16-row passes (full-row dwordx4 stores kill the 2x write amplification).
__global__ __launch_bounds__(256, 4) void tail_fused_kernel(
    const u16* __restrict__ accb, const u16* __restrict__ woutT,
    const float* __restrict__ b_out, const float* __restrict__ query,
    const float* __restrict__ g1, const float* __restrict__ beta1,
    const u16* __restrict__ w1T, const float* __restrict__ b1,
    const u16* __restrict__ w2T, const float* __restrict__ b2,
    const float* __restrict__ g2, const float* __restrict__ beta2,
    float* __restrict__ out, int M) {
  __shared__ uint4 smem[2112];             // 33,792 B total
  uint4* As = smem;                        // 16 KB: accb stage, then h
  uint4* Xs = smem + 1024;                 // 16 KB: x (LN1 out)
  float2* pnorm = (float2*)(smem + 2048);  // 1 KB: 32 rows x 4 waves
  const int tid = threadIdx.x;
  const int w = tid >> 6, lane = tid & 63, quad = lane >> 4, l16 = lane & 15;
  const int r0 = blockIdx.x * 32;
  // stage accb (32 rows x 512 B) via DMA, source-side swizzle
#pragma unroll
  for (int jj = 0; jj < 4; ++jj) {
    int row = w * 8 + jj * 2 + (lane >> 5);
    int gr = min(r0 + row, M - 1);
    int c = lane & 31;
    const uint4* gp = (const uint4*)accb + (size_t)gr * 32 + (c ^ (row & 7));
    __builtin_amdgcn_global_load_lds(
        (const __attribute__((address_space(1))) void*)gp,
        (__attribute__((address_space(3))) void*)(As + (w * 8 + jj * 2) * 32),
        16, 0, 0);
  }
  __syncthreads();
  i16x8 bfr[8];
  f32x4 vals[4][2];
  float s[8], s2[8];

  // ---------- stage 1: out-proj GEMM + query resid + LN1 stats ----------
#pragma unroll
  for (int i = 0; i < 4; ++i) {
    load_b(bfr, woutT, w * 4 + i, l16, quad);
    tile_mfma2(vals[i], As, bfr, l16, quad);
  }
#pragma unroll
  for (int k = 0; k < 8; ++k) { s[k] = 0.f; s2[k] = 0.f; }
#pragma unroll
  for (int i = 0; i < 4; ++i) {
    const int col = (w * 4 + i) * 16 + l16;
    const float bv = b_out[col];
#pragma unroll
    for (int rg = 0; rg < 2; ++rg)
#pragma unroll
      for (int r = 0; r < 4; ++r) {
        int row = r0 + rg * 16 + (quad << 2) + r;
        float rv = (row < M) ? query[row * 256 + col] : 0.f;
        float v = vals[i][rg][r] + bv + rv;
        vals[i][rg][r] = v;
        s[rg * 4 + r] += v; s2[rg * 4 + r] += v * v;
      }
  }
#pragma unroll
  for (int k = 0; k < 8; ++k)
#pragma unroll
    for (int o = 1; o < 16; o <<= 1) {
      s[k] += __shfl_xor(s[k], o);
      s2[k] += __shfl_xor(s2[k], o);
    }
  if (l16 == 0) {
#pragma unroll
    for (int rg = 0; rg < 2; ++rg)
#pragma unroll
      for (int r = 0; r < 4; ++r)
        pnorm[(rg * 16 + (quad << 2) + r) * 4 + w] = make_float2(s[rg * 4 + r], s2[rg * 4 + r]);
  }
  __syncthreads();
  // LN1 normalize -> Xs (bf16, swizzled A layout)
  u16* Xu = (u16*)Xs;
#pragma unroll
  for (int rg = 0; rg < 2; ++rg)
#pragma unroll
    for (int r = 0; r < 4; ++r) {
      int lrow = rg * 16 + (quad << 2) + r;
      float4 p01 = ((const float4*)pnorm)[lrow * 2];
      float4 p23 = ((const float4*)pnorm)[lrow * 2 + 1];
      float ss = p01.x + p01.z + p23.x + p23.z;
      float qq = p01.y + p01.w + p23.y + p23.w;
      float mean = ss * (1.f / 256.f);
      float var = qq * (1.f / 256.f) - mean * mean;
      float inv = rsqrtf(var + 1e-5f);
#pragma unroll
      for (int i = 0; i < 4; ++i) {
        const int col = (w * 4 + i) * 16 + l16;
        float o = (vals[i][rg][r] - mean) * inv * g1[col] + beta1[col];
        Xu[swz_u16(lrow, col)] = f2bf(o);
      }
    }
  __syncthreads();  // Xs ready; As free

  // ---------- stage 2: FFN1 = relu(x @ w1 + b1) -> h into As ----------
#pragma unroll
  for (int i = 0; i < 4; ++i) {
    load_b(bfr, w1T, w * 4 + i, l16, quad);
    tile_mfma2(vals[i], Xs, bfr, l16, quad);
  }
  u16* Hu = (u16*)As;
#pragma unroll
  for (int i = 0; i < 4; ++i) {
    const int col = (w * 4 + i) * 16 + l16;
    const float bv = b1[col];
#pragma unroll
    for (int rg = 0; rg < 2; ++rg)
#pragma unroll
      for (int r = 0; r < 4; ++r) {
        int lrow = rg * 16 + (quad << 2) + r;
        Hu[swz_u16(lrow, col)] = f2bf(fmaxf(vals[i][rg][r] + bv, 0.f));
      }
  }
  __syncthreads();  // h ready

  // ---------- stage 3: FFN2 = h @ w2 + b2 + x, LN2 stats ----------
#pragma unroll
  for (int i = 0; i < 4; ++i) {
    load_b(bfr, w2T, w * 4 + i, l16, quad);
    tile_mfma2(vals[i], As, bfr, l16, quad);
  }
#pragma unroll
  for (int k = 0; k < 8; ++k) { s[k] = 0.f; s2[k] = 0.f; }
#pragma unroll
  for (int i = 0; i < 4; ++i) {
    const int col = (w * 4 + i) * 16 + l16;
    const float bv = b2[col];
#pragma unroll
    for (int rg = 0; rg < 2; ++rg)
#pragma unroll
      for (int r = 0; r < 4; ++r) {
        int lrow = rg * 16 + (quad << 2) + r;
        float xv = bf2f(Xu[swz_u16(lrow, col)]);
        float v = vals[i][rg][r] + bv + xv;
        vals[i][rg][r] = v;
        s[rg * 4 + r] += v; s2[rg * 4 + r] += v * v;
      }
  }
#pragma unroll
  for (int k = 0; k < 8; ++k)
#pragma unroll
    for (int o = 1; o < 16; o <<= 1) {
      s[k] += __shfl_xor(s[k], o);
      s2[k] += __shfl_xor(s2[k], o);
    }
  if (l16 == 0) {
#pragma unroll
    for (int rg = 0; rg < 2; ++rg)
#pragma unroll
      for (int r = 0; r < 4; ++r)
        pnorm[(rg * 16 + (quad << 2) + r) * 4 + w] = make_float2(s[rg * 4 + r], s2[rg * 4 + r]);
  }
  __syncthreads();
  // ---------- LN2 + f32 out via LDS (two 16-row passes, full-row stores) ----------
  float* stg = (float*)smem;  // 16 rows x stride 268 f32 = 17,152 B (As+head of Xs; both dead)
#pragma unroll
  for (int rg = 0; rg < 2; ++rg) {
#pragma unroll
    for (int r = 0; r < 4; ++r) {
      int lrow = rg * 16 + (quad << 2) + r;
      float4 p01 = ((const float4*)pnorm)[lrow * 2];
      float4 p23 = ((const float4*)pnorm)[lrow * 2 + 1];
      float ss = p01.x + p01.z + p23.x + p23.z;
      float qq = p01.y + p01.w + p23.y + p23.w;
      float mean = ss * (1.f / 256.f);
      float var = qq * (1.f / 256.f) - mean * mean;
      float inv = rsqrtf(var + 1e-5f);
#pragma unroll
      for (int i = 0; i < 4; ++i) {
        const int col = (w * 4 + i) * 16 + l16;
        stg[((quad << 2) + r) * 268 + col] = (vals[i][rg][r] - mean) * inv * g2[col] + beta2[col];
      }
    }
    __syncthreads();
#pragma unroll
    for (int rr = 0; rr < 4; ++rr) {
      int lr = w * 4 + rr;
      int grow = r0 + rg * 16 + lr;
      if (grow < M)
        *(float4*)(out + (size_t)grow * 256 + lane * 4) =
            *(const float4*)(stg + lr * 268 + lane * 4);
    }
    if (rg == 0) __syncthreads();
  }
}

// ---- fused prep + deformable sampling: one block = 4 queries ----
__global__ __launch_bounds__(256) void sampler_kernel(
    const float* __restrict__ refp, const u16* __restrict__ offb,
    const float* __restrict__ aw, const u16* __restrict__ value,
    u32* __restrict__ accv) {
  __shared__ uint4 rec[544];
  const int t = threadIdx.x;
  // bijective chunked XCD swizzle (m204 variant)
  const int nwg = gridDim.x;
  const int qd = nwg >> 3, rm = nwg & 7;
  const int xcd = blockIdx.x & 7, ii = blockIdx.x >> 3;
  const int b = (xcd < rm ? xcd * (qd + 1) : rm * (qd + 1) + (xcd - rm) * qd) + ii;
#pragma unroll
  for (int it = 0; it < 2; ++it) {
    const int sidx = t + it * 256;
    const int qs = sidx >> 7, j = sidx & 127;
    const int i = b * 4 + qs;
    if (i < LQ) {
      const int h = j >> 4, lp = j & 15, l = lp >> 2;
      const int Wl = (l == 0) ? 180 : (l == 1) ? 90 : (l == 2) ? 45 : 23;
      const int st = (l == 0) ? 0 : (l == 1) ? 32400 : (l == 2) ? 40500 : 42525;
      const float wj = aw[i * 128 + j];
      const u32 o2 = *(const u32*)(offb + i * 256 + h * 32 + lp * 2);
      const float ox = bf2f((u16)(o2 & 0xffffu)), oy = bf2f((u16)(o2 >> 16));
      const float rx = refp[i * 8 + l * 2], ry = refp[i * 8 + l * 2 + 1];
      float x = rx * (float)Wl + ox - 0.5f;
      float y = ry * (float)Wl + oy - 0.5f;
      float x0f = floorf(x), y0f = floorf(y);
      float fx = x - x0f, fy = y - y0f;
      int x0 = (int)x0f, y0 = (int)y0f;
      bool vx0 = (x0 >= 0) & (x0 < Wl), vx1 = (x0 + 1 >= 0) & (x0 + 1 < Wl);
      bool vy0 = (y0 >= 0) & (y0 < Wl), vy1 = (y0 + 1 >= 0) & (y0 + 1 < Wl);
      int x0c = min(max(x0, 0), Wl - 1), x1c = min(max(x0 + 1, 0), Wl - 1);
      int y0c = min(max(y0, 0), Wl - 1), y1c = min(max(y0 + 1, 0), Wl - 1);
      float w00 = (vx0 & vy0) ? wj * (1.f - fx) * (1.f - fy) : 0.f;
      float w01 = (vx1 & vy0) ? wj * fx * (1.f - fy) : 0.f;
      float w10 = (vx0 & vy1) ? wj * (1.f - fx) * fy : 0.f;
      float w11 = (vx1 & vy1) ? wj * fx * fy : 0.f;
      uint4 r;
      r.x = (u32)((st + y0c * Wl + x0c) * 512 + h * 64) | (u32)(x1c - x0c);
      r.y = (u32)(y1c - y0c) * (u32)(Wl * 512);
      r.z = (u32)f2bf(w00) | ((u32)f2bf(w01) << 16);
      r.w = (u32)f2bf(w10) | ((u32)f2bf(w11) << 16);
      rec[qs * 136 + h * 17 + lp] = r;
    }
  }
  __syncthreads();
  const int qs = t >> 6, j2 = t & 63;
  const int h = j2 >> 3, dp8 = j2 & 7;
  const int i = b * 4 + qs;
  if (i >= LQ) return;
  const char* vb = (const char*)value;
  float a0 = 0.f, a1 = 0.f, a2 = 0.f, a3 = 0.f;
  const int rbase = qs * 136 + h * 17;
  const u32 dpo = (u32)(dp8 * 8);
#pragma unroll
  for (int p = 0; p < 16; ++p) {
    uint4 r = rec[rbase + p];
    u32 base = (r.x & 0xFFFFFFFEu) + dpo;
    u32 dxo = (r.x & 1u) << 9;
    u32 dyo = r.y;
    uint2 p00 = *(const uint2*)(vb + base);
    uint2 p01 = *(const uint2*)(vb + base + dxo);
    uint2 p10 = *(const uint2*)(vb + base + dyo);
    uint2 p11 = *(const uint2*)(vb + base + dyo + dxo);
    a0 = dot2bf(__builtin_amdgcn_perm(p01.x, p00.x, 0x05040100u), r.z, a0);
    a1 = dot2bf(__builtin_amdgcn_perm(p01.x, p00.x, 0x07060302u), r.z, a1);
    a2 = dot2bf(__builtin_amdgcn_perm(p01.y, p00.y, 0x05040100u), r.z, a2);
    a3 = dot2bf(__builtin_amdgcn_perm(p01.y, p00.y, 0x07060302u), r.z, a3);
    a0 = dot2bf(__builtin_amdgcn_perm(p11.x, p10.x, 0x05040100u), r.w, a0);
    a1 = dot2bf(__builtin_amdgcn_perm(p11.x, p10.x, 0x07060302u), r.w, a1);
    a2 = dot2bf(__builtin_amdgcn_perm(p11.y, p10.y, 0x05040100u), r.w, a2);
    a3 = dot2bf(__builtin_amdgcn_perm(p11.y, p10.y, 0x07060302u), r.w, a3);
  }
  uint2 pk;
  pk.x = (u32)f2bf(a0) | ((u32)f2bf(a1) << 16);
  pk.y = (u32)f2bf(a2) | ((u32)f2bf(a3) << 16);
  ((uint2*)accv)[i * 64 + h * 8 + dp8] = pk;
}

extern "C" void kernel_launch(void* const* d_in, const int* in_sizes, int n_in,
                              void* d_out, int out_size, void* d_ws, size_t ws_size,
                              hipStream_t stream) {
  const float* query  = (const float*)d_in[0];
  const float* refp   = (const float*)d_in[1];
  const float* pos    = (const float*)d_in[2];
  const float* w_off  = (const float*)d_in[5];
  const float* b_off  = (const float*)d_in[6];
  const float* w_attn = (const float*)d_in[7];
  const float* b_attn = (const float*)d_in[8];
  const float* w_val  = (const float*)d_in[9];
  const float* b_val  = (const float*)d_in[10];
  const float* w_out  = (const float*)d_in[11];
  const float* b_out  = (const float*)d_in[12];
  const float* g1     = (const float*)d_in[13];
  const float* beta1  = (const float*)d_in[14];
  const float* w1     = (const float*)d_in[15];
  const float* b1     = (const float*)d_in[16];
  const float* w2     = (const float*)d_in[17];
  const float* b2     = (const float*)d_in[18];
  const float* g2     = (const float*)d_in[19];
  const float* beta2  = (const float*)d_in[20];

  char* ws = (char*)d_ws;
  u16*   wT    = (u16*)(ws + 0);            //   720,896, live whole launch
  u16*   value = (u16*)(ws + 720896);       // dead after sampler
  u16*   offb  = (u16*)(ws + 22764544);     // dead after sampler
  float* aw    = (float*)(ws + 44808192);   // dead after sampler
  u16*   accb  = (u16*)(ws + 66851840);     // dead after tail

  u16* woffT  = wT;                // 256 rows; wattnT contiguous after (384-row B)
  u16* wvalT  = wT + 98304;
  u16* woutT  = wT + 163840;
  u16* w1T    = wT + 229376;
  u16* w2T    = wT + 294912;

  transpose_all_kernel<<<1408, 256, 0, stream>>>(w_off, w_attn, w_val, w_out, w1, w2, wT);

  const int gm = (LQ + 63) / 64;  // 673
  gemm_kernel<0, 1><<<gm, 256, 0, stream>>>(query, wvalT, b_val, value, LQ);
  offaw_gemm_kernel<<<gm, 256, 0, stream>>>(query, pos, woffT, b_off, b_attn, offb, aw, LQ);
  const int sb = (LQ + 3) / 4;  // 10764
  sampler_kernel<<<sb, 256, 0, stream>>>(refp, offb, aw, value, (u32*)accb);
  const int gt = (LQ + 31) / 32;  // 1346
  tail_fused_kernel<<<gt, 256, 0, stream>>>(accb, woutT, b_out, query, g1, beta1,
                                            w1T, b1, w2T, b2, g2, beta2,
                                            (float*)d_out, LQ);
}

// Round 5
// 393.430 us; speedup vs baseline: 1.1785x; 1.0025x over previous
//
#include <hip/hip_runtime.h>

typedef unsigned short u16;
typedef unsigned int u32;
typedef float f32x4 __attribute__((ext_vector_type(4)));
typedef short i16x8 __attribute__((ext_vector_type(8)));
typedef __bf16 bf16x8_t __attribute__((ext_vector_type(8)));

#define LQ 43054

__device__ __forceinline__ float bf2f(u16 u) {
  union { u32 i; float f; } v; v.i = ((u32)u) << 16; return v.f;
}
__device__ __forceinline__ u16 f2bf(float f) {
  u32 i = __float_as_uint(f);
  return (u16)((i + 0x7FFFu + ((i >> 16) & 1u)) >> 16);
}

// D = S0.lo*S1.lo + S0.hi*S1.hi + S2  (bf16 pairs, f32 accumulate)
__device__ __forceinline__ float dot2bf(u32 v, u32 w, float c) {
  float d;
  asm("v_dot2_f32_bf16 %0, %1, %2, %3" : "=v"(d) : "v"(v), "v"(w), "v"(c));
  return d;
}

// ---- MFMA wrapper robust to builtin operand type (V8 short vs V8 __bf16) ----
template <typename T>
__device__ __forceinline__ auto mfma_try(T a, T b, f32x4 c, int)
    -> decltype(__builtin_amdgcn_mfma_f32_16x16x32_bf16(a, b, c, 0, 0, 0)) {
  return __builtin_amdgcn_mfma_f32_16x16x32_bf16(a, b, c, 0, 0, 0);
}
template <typename T>
__device__ __forceinline__ f32x4 mfma_try(T a, T b, f32x4 c, long) {
  return __builtin_amdgcn_mfma_f32_16x16x32_bf16(
      __builtin_bit_cast(bf16x8_t, a), __builtin_bit_cast(bf16x8_t, b), c, 0, 0, 0);
}
__device__ __forceinline__ f32x4 mfma_bf16(i16x8 a, i16x8 b, f32x4 c) {
  return mfma_try(a, b, c, 0);
}

// ---- all 6 weight transposes in one kernel: f32 (256 x N) -> bf16 (N x 256) ----
__global__ void transpose_all_kernel(
    const float* __restrict__ w_off, const float* __restrict__ w_attn,
    const float* __restrict__ w_val, const float* __restrict__ w_out,
    const float* __restrict__ w1, const float* __restrict__ w2,
    u16* __restrict__ wT) {
  int b = blockIdx.x;
  const float* src; u16* dst; int N; int col;
  if (b < 256)       { src = w_off;  dst = wT;          N = 256; col = b; }
  else if (b < 384)  { src = w_attn; dst = wT + 65536;  N = 128; col = b - 256; }
  else if (b < 640)  { src = w_val;  dst = wT + 98304;  N = 256; col = b - 384; }
  else if (b < 896)  { src = w_out;  dst = wT + 163840; N = 256; col = b - 640; }
  else if (b < 1152) { src = w1;     dst = wT + 229376; N = 256; col = b - 896; }
  else               { src = w2;     dst = wT + 294912; N = 256; col = b - 1152; }
  dst[col * 256 + threadIdx.x] = f2bf(src[threadIdx.x * N + col]);
}

// ================= shared helpers ==========================================
// load one 16-col B tile's 8 K-fragments into registers
__device__ __forceinline__ void load_b(i16x8* f, const u16* Bt, int t, int l16, int quad) {
  const uint4* bp = (const uint4*)Bt + (t * 16 + l16) * 32 + quad;
#pragma unroll
  for (int kk = 0; kk < 8; ++kk) f[kk] = __builtin_bit_cast(i16x8, bp[kk << 2]);
}
// 16 MFMAs of one tile over 2 row-groups (32-row blocks)
__device__ __forceinline__ void tile_mfma2(f32x4* acc, const uint4* As,
                                           const i16x8* bfr, int l16, int quad) {
#pragma unroll
  for (int rg = 0; rg < 2; ++rg) {
    int arow = rg * 16 + l16;
    f32x4 a = {0.f, 0.f, 0.f, 0.f};
#pragma unroll
    for (int kk = 0; kk < 8; ++kk) {
      i16x8 afr = __builtin_bit_cast(i16x8, As[arow * 32 + (((kk << 2) + quad) ^ (arow & 7))]);
      a = mfma_bf16(afr, bfr[kk], a);
    }
    acc[rg] = a;
  }
}

// u16 index into a GEMM-A swizzled LDS tile for element (row, col)
__device__ __forceinline__ int swz_u16(int row, int col) {
  return row * 256 + ((((col >> 3) ^ (row & 7)) << 3) | (col & 7));
}

// LDS output staging: u16 rows with stride 264 (528 B: 16B-aligned, bank-skewed).
#define LS_STRIDE 264

// ---- fused head: value GEMM + offsets GEMM + attn softmax, one query read ----
// 32 rows/block, LDS 33.8 KB -> 4 blocks/CU. Aq = bf16(query), Aqp = bf16(q+pos).
// Arithmetic identical to the previous separate value/offaw kernels.
__global__ __launch_bounds__(256, 4) void valoff_kernel(
    const float* __restrict__ query, const float* __restrict__ pos,
    const u16* __restrict__ wvalT, const float* __restrict__ b_val,
    const u16* __restrict__ woffT, const float* __restrict__ b_off,
    const float* __restrict__ b_attn,
    u16* __restrict__ value, u16* __restrict__ offb, float* __restrict__ aw,
    int M) {
  __shared__ uint4 smem[2112];   // 33,792 B
  uint4* Aq  = smem;             // 17,408 B region: bf16(query); reused as LS
  uint4* Aqp = smem + 1088;      // 16 KB: bf16(query+pos)
  const int tid = threadIdx.x;
  const int w = tid >> 6, lane = tid & 63, quad = lane >> 4, l16 = lane & 15;
  const int r0 = blockIdx.x * 32;
  // ---- stage: single query+pos read -> both A tiles ----
#pragma unroll
  for (int h = 0; h < 2; ++h) {
    float4 vq[4], vp[4];
#pragma unroll
    for (int it = 0; it < 4; ++it) {
      int e = tid + (h * 4 + it) * 256;
      int gr = min(r0 + (e >> 6), M - 1);
      int idx = gr * 64 + (e & 63);
      vq[it] = ((const float4*)query)[idx];
      vp[it] = ((const float4*)pos)[idx];
    }
#pragma unroll
    for (int it = 0; it < 4; ++it) {
      int e = tid + (h * 4 + it) * 256;
      int row = e >> 6, c4 = e & 63;
      int c = c4 >> 1, hf = c4 & 1;
      int sidx = ((row * 32 + (c ^ (row & 7))) << 1) | hf;
      uint2 pkq, pks;
      pkq.x = (u32)f2bf(vq[it].x) | ((u32)f2bf(vq[it].y) << 16);
      pkq.y = (u32)f2bf(vq[it].z) | ((u32)f2bf(vq[it].w) << 16);
      float sx = vq[it].x + vp[it].x, sy = vq[it].y + vp[it].y;
      float sz = vq[it].z + vp[it].z, sw = vq[it].w + vp[it].w;
      pks.x = (u32)f2bf(sx) | ((u32)f2bf(sy) << 16);
      pks.y = (u32)f2bf(sz) | ((u32)f2bf(sw) << 16);
      ((uint2*)Aq)[sidx] = pkq;
      ((uint2*)Aqp)[sidx] = pks;
    }
  }
  __syncthreads();  // S1
  i16x8 bfr[8];
  f32x4 vals[4][2];
  // ---- value tiles (Aq @ wvalT) ----
#pragma unroll
  for (int i = 0; i < 4; ++i) {
    load_b(bfr, wvalT, w * 4 + i, l16, quad);
    tile_mfma2(vals[i], Aq, bfr, l16, quad);
  }
  // ---- attn tiles (Aqp @ wattnT) + per-head softmax (16 vals/head) ----
#pragma unroll
  for (int i = 0; i < 2; ++i) {
    const int t = w + 4 * i;
    f32x4 acc[2];
    load_b(bfr, woffT, 16 + t, l16, quad);   // wattnT contiguous after off tiles
    tile_mfma2(acc, Aqp, bfr, l16, quad);
    const int colc = t * 16 + l16;
    const float bv = b_attn[colc];
#pragma unroll
    for (int rg = 0; rg < 2; ++rg)
#pragma unroll
      for (int r = 0; r < 4; ++r) {
        float v = acc[rg][r] + bv;
        float m = v;
#pragma unroll
        for (int o = 1; o < 16; o <<= 1) m = fmaxf(m, __shfl_xor(m, o));
        float e = __expf(v - m);
        float s = e;
#pragma unroll
        for (int o = 1; o < 16; o <<= 1) s += __shfl_xor(s, o);
        int row = r0 + rg * 16 + (quad << 2) + r;
        if (row < M) aw[row * 128 + colc] = e / s;
      }
  }
  __syncthreads();  // S2: all Aq reads done
  // ---- value epilogue via LS (over dead Aq region), vectorized stores ----
  u16* Ls = (u16*)smem;
#pragma unroll
  for (int i = 0; i < 4; ++i) {
    const int col = (w * 4 + i) * 16 + l16;
    const float bv = b_val[col];
#pragma unroll
    for (int rg = 0; rg < 2; ++rg)
#pragma unroll
      for (int r = 0; r < 4; ++r)
        Ls[(rg * 16 + (quad << 2) + r) * LS_STRIDE + col] = f2bf(vals[i][rg][r] + bv);
  }
  __syncthreads();  // S3
#pragma unroll
  for (int it = 0; it < 4; ++it) {
    int lrow = w * 8 + it * 2 + (lane >> 5);
    int grow = r0 + lrow;
    if (grow < M)
      *(uint4*)(value + (size_t)grow * 256 + (lane & 31) * 8) =
          *(const uint4*)(Ls + lrow * LS_STRIDE + (lane & 31) * 8);
  }
  // ---- off tiles (Aqp @ woffT) ----
#pragma unroll
  for (int i = 0; i < 4; ++i) {
    load_b(bfr, woffT, w * 4 + i, l16, quad);
    tile_mfma2(vals[i], Aqp, bfr, l16, quad);
  }
  __syncthreads();  // S4: value-store LS reads done
#pragma unroll
  for (int i = 0; i < 4; ++i) {
    const int col = (w * 4 + i) * 16 + l16;
    const float bv = b_off[col];
#pragma unroll
    for (int rg = 0; rg < 2; ++rg)
#pragma unroll
      for (int r = 0; r < 4; ++r)
        Ls[(rg * 16 + (quad << 2) + r) * LS_STRIDE + col] = f2bf(vals[i][rg][r] + bv);
  }
  __syncthreads();  // S5
#pragma unroll
  for (int it = 0; it < 4; ++it) {
    int lrow = w * 8 + it * 2 + (lane >> 5);
    int grow = r0 + lrow;
    if (grow < M)
      *(uint4*)(offb + (size_t)grow * 256 + (lane & 31) * 8) =
          *(const uint4*)(Ls + lrow * LS_STRIDE + (lane & 31) * 8);
  }
}

// ---- fused tail: out-proj -> +query -> LN1 -> FFN1(relu) -> FFN2 -> +x -> LN2 ----
// 32 rows/block (4 blocks/CU). Unchanged from round 4 (~76 us).
__global__ __launch_bounds__(256, 4) void tail_fused_kernel(
    const u16* __restrict__ accb, const u16* __restrict__ woutT,
    const float* __restrict__ b_out, const float* __restrict__ query,
    const float* __restrict__ g1, const float* __restrict__ beta1,
    const u16* __restrict__ w1T, const float* __restrict__ b1,
    const u16* __restrict__ w2T, const float* __restrict__ b2,
    const float* __restrict__ g2, const float* __restrict__ beta2,
    float* __restrict__ out, int M) {
  __shared__ uint4 smem[2112];             // 33,792 B total
  uint4* As = smem;                        // 16 KB: accb stage, then h
  uint4* Xs = smem + 1024;                 // 16 KB: x (LN1 out)
  float2* pnorm = (float2*)(smem + 2048);  // 1 KB
  const int tid = threadIdx.x;
  const int w = tid >> 6, lane = tid & 63, quad = lane >> 4, l16 = lane & 15;
  const int r0 = blockIdx.x * 32;
#pragma unroll
  for (int jj = 0; jj < 4; ++jj) {
    int row = w * 8 + jj * 2 + (lane >> 5);
    int gr = min(r0 + row, M - 1);
    int c = lane & 31;
    const uint4* gp = (const uint4*)accb + (size_t)gr * 32 + (c ^ (row & 7));
    __builtin_amdgcn_global_load_lds(
        (const __attribute__((address_space(1))) void*)gp,
        (__attribute__((address_space(3))) void*)(As + (w * 8 + jj * 2) * 32),
        16, 0, 0);
  }
  __syncthreads();
  i16x8 bfr[8];
  f32x4 vals[4][2];
  float s[8], s2[8];

  // ---------- stage 1: out-proj GEMM + query resid + LN1 stats ----------
#pragma unroll
  for (int i = 0; i < 4; ++i) {
    load_b(bfr, woutT, w * 4 + i, l16, quad);
    tile_mfma2(vals[i], As, bfr, l16, quad);
  }
#pragma unroll
  for (int k = 0; k < 8; ++k) { s[k] = 0.f; s2[k] = 0.f; }
#pragma unroll
  for (int i = 0; i < 4; ++i) {
    const int col = (w * 4 + i) * 16 + l16;
    const float bv = b_out[col];
#pragma unroll
    for (int rg = 0; rg < 2; ++rg)
#pragma unroll
      for (int r = 0; r < 4; ++r) {
        int row = r0 + rg * 16 + (quad << 2) + r;
        float rv = (row < M) ? query[row * 256 + col] : 0.f;
        float v = vals[i][rg][r] + bv + rv;
        vals[i][rg][r] = v;
        s[rg * 4 + r] += v; s2[rg * 4 + r] += v * v;
      }
  }
#pragma unroll
  for (int k = 0; k < 8; ++k)
#pragma unroll
    for (int o = 1; o < 16; o <<= 1) {
      s[k] += __shfl_xor(s[k], o);
      s2[k] += __shfl_xor(s2[k], o);
    }
  if (l16 == 0) {
#pragma unroll
    for (int rg = 0; rg < 2; ++rg)
#pragma unroll
      for (int r = 0; r < 4; ++r)
        pnorm[(rg * 16 + (quad << 2) + r) * 4 + w] = make_float2(s[rg * 4 + r], s2[rg * 4 + r]);
  }
  __syncthreads();
  u16* Xu = (u16*)Xs;
#pragma unroll
  for (int rg = 0; rg < 2; ++rg)
#pragma unroll
    for (int r = 0; r < 4; ++r) {
      int lrow = rg * 16 + (quad << 2) + r;
      float4 p01 = ((const float4*)pnorm)[lrow * 2];
      float4 p23 = ((const float4*)pnorm)[lrow * 2 + 1];
      float ss = p01.x + p01.z + p23.x + p23.z;
      float qq = p01.y + p01.w + p23.y + p23.w;
      float mean = ss * (1.f / 256.f);
      float var = qq * (1.f / 256.f) - mean * mean;
      float inv = rsqrtf(var + 1e-5f);
#pragma unroll
      for (int i = 0; i < 4; ++i) {
        const int col = (w * 4 + i) * 16 + l16;
        float o = (vals[i][rg][r] - mean) * inv * g1[col] + beta1[col];
        Xu[swz_u16(lrow, col)] = f2bf(o);
      }
    }
  __syncthreads();

  // ---------- stage 2: FFN1 = relu(x @ w1 + b1) -> h into As ----------
#pragma unroll
  for (int i = 0; i < 4; ++i) {
    load_b(bfr, w1T, w * 4 + i, l16, quad);
    tile_mfma2(vals[i], Xs, bfr, l16, quad);
  }
  u16* Hu = (u16*)As;
#pragma unroll
  for (int i = 0; i < 4; ++i) {
    const int col = (w * 4 + i) * 16 + l16;
    const float bv = b1[col];
#pragma unroll
    for (int rg = 0; rg < 2; ++rg)
#pragma unroll
      for (int r = 0; r < 4; ++r) {
        int lrow = rg * 16 + (quad << 2) + r;
        Hu[swz_u16(lrow, col)] = f2bf(fmaxf(vals[i][rg][r] + bv, 0.f));
      }
  }
  __syncthreads();

  // ---------- stage 3: FFN2 = h @ w2 + b2 + x, LN2 stats ----------
#pragma unroll
  for (int i = 0; i < 4; ++i) {
    load_b(bfr, w2T, w * 4 + i, l16, quad);
    tile_mfma2(vals[i], As, bfr, l16, quad);
  }
#pragma unroll
  for (int k = 0; k < 8; ++k) { s[k] = 0.f; s2[k] = 0.f; }
#pragma unroll
  for (int i = 0; i < 4; ++i) {
    const int col = (w * 4 + i) * 16 + l16;
    const float bv = b2[col];
#pragma unroll
    for (int rg = 0; rg < 2; ++rg)
#pragma unroll
      for (int r = 0; r < 4; ++r) {
        int lrow = rg * 16 + (quad << 2) + r;
        float xv = bf2f(Xu[swz_u16(lrow, col)]);
        float v = vals[i][rg][r] + bv + xv;
        vals[i][rg][r] = v;
        s[rg * 4 + r] += v; s2[rg * 4 + r] += v * v;
      }
  }
#pragma unroll
  for (int k = 0; k < 8; ++k)
#pragma unroll
    for (int o = 1; o < 16; o <<= 1) {
      s[k] += __shfl_xor(s[k], o);
      s2[k] += __shfl_xor(s2[k], o);
    }
  if (l16 == 0) {
#pragma unroll
    for (int rg = 0; rg < 2; ++rg)
#pragma unroll
      for (int r = 0; r < 4; ++r)
        pnorm[(rg * 16 + (quad << 2) + r) * 4 + w] = make_float2(s[rg * 4 + r], s2[rg * 4 + r]);
  }
  __syncthreads();
  float* stg = (float*)smem;
#pragma unroll
  for (int rg = 0; rg < 2; ++rg) {
#pragma unroll
    for (int r = 0; r < 4; ++r) {
      int lrow = rg * 16 + (quad << 2) + r;
      float4 p01 = ((const float4*)pnorm)[lrow * 2];
      float4 p23 = ((const float4*)pnorm)[lrow * 2 + 1];
      float ss = p01.x + p01.z + p23.x + p23.z;
      float qq = p01.y + p01.w + p23.y + p23.w;
      float mean = ss * (1.f / 256.f);
      float var = qq * (1.f / 256.f) - mean * mean;
      float inv = rsqrtf(var + 1e-5f);
#pragma unroll
      for (int i = 0; i < 4; ++i) {
        const int col = (w * 4 + i) * 16 + l16;
        stg[((quad << 2) + r) * 268 + col] = (vals[i][rg][r] - mean) * inv * g2[col] + beta2[col];
      }
    }
    __syncthreads();
#pragma unroll
    for (int rr = 0; rr < 4; ++rr) {
      int lr = w * 4 + rr;
      int grow = r0 + rg * 16 + lr;
      if (grow < M)
        *(float4*)(out + (size_t)grow * 256 + lane * 4) =
            *(const float4*)(stg + lr * 268 + lane * 4);
    }
    if (rg == 0) __syncthreads();
  }
}

// ---- fused prep + deformable sampling: one block = 2 queries (round-2 config,
// measured 75.4 us: 2*LQ waves of TLP, u32 taps, dot2 accumulate) ----
__global__ __launch_bounds__(256) void sampler_kernel(
    const float* __restrict__ refp, const u16* __restrict__ offb,
    const float* __restrict__ aw, const u16* __restrict__ value,
    u32* __restrict__ accv) {
  __shared__ uint4 rec[272];
  const int t = threadIdx.x;
  const int b = blockIdx.x;
  {
    const int qs = t >> 7, j = t & 127;
    const int i = b * 2 + qs;
    const int h = j >> 4, lp = j & 15, l = lp >> 2;
    const int Wl = (l == 0) ? 180 : (l == 1) ? 90 : (l == 2) ? 45 : 23;
    const int st = (l == 0) ? 0 : (l == 1) ? 32400 : (l == 2) ? 40500 : 42525;
    const float wj = aw[i * 128 + j];
    const u32 o2 = *(const u32*)(offb + i * 256 + h * 32 + lp * 2);
    const float ox = bf2f((u16)(o2 & 0xffffu)), oy = bf2f((u16)(o2 >> 16));
    const float rx = refp[i * 8 + l * 2], ry = refp[i * 8 + l * 2 + 1];
    float x = rx * (float)Wl + ox - 0.5f;
    float y = ry * (float)Wl + oy - 0.5f;
    float x0f = floorf(x), y0f = floorf(y);
    float fx = x - x0f, fy = y - y0f;
    int x0 = (int)x0f, y0 = (int)y0f;
    bool vx0 = (x0 >= 0) & (x0 < Wl), vx1 = (x0 + 1 >= 0) & (x0 + 1 < Wl);
    bool vy0 = (y0 >= 0) & (y0 < Wl), vy1 = (y0 + 1 >= 0) & (y0 + 1 < Wl);
    int x0c = min(max(x0, 0), Wl - 1), x1c = min(max(x0 + 1, 0), Wl - 1);
    int y0c = min(max(y0, 0), Wl - 1), y1c = min(max(y0 + 1, 0), Wl - 1);
    float w00 = (vx0 & vy0) ? wj * (1.f - fx) * (1.f - fy) : 0.f;
    float w01 = (vx1 & vy0) ? wj * fx * (1.f - fy) : 0.f;
    float w10 = (vx0 & vy1) ? wj * (1.f - fx) * fy : 0.f;
    float w11 = (vx1 & vy1) ? wj * fx * fy : 0.f;
    uint4 r;
    r.x = (u32)((st + y0c * Wl + x0c) * 512 + h * 64) | (u32)(x1c - x0c);
    r.y = (u32)(y1c - y0c) * (u32)(Wl * 512);
    r.z = (u32)f2bf(w00) | ((u32)f2bf(w01) << 16);
    r.w = (u32)f2bf(w10) | ((u32)f2bf(w11) << 16);
    rec[qs * 136 + h * 17 + lp] = r;
  }
  __syncthreads();
  const int qs = t >> 7, j = t & 127;
  const int h = j >> 4, dp = j & 15;
  const char* vb = (const char*)value;
  float a0 = 0.f, a1 = 0.f;
  const int rbase = qs * 136 + h * 17;
  const u32 dp4 = (u32)(dp * 4);
#pragma unroll
  for (int p = 0; p < 16; ++p) {
    uint4 r = rec[rbase + p];
    u32 base = (r.x & 0xFFFFFFFEu) + dp4;
    u32 dxo = (r.x & 1u) << 9;
    u32 dyo = r.y;
    u32 p00 = *(const u32*)(vb + base);
    u32 p01 = *(const u32*)(vb + base + dxo);
    u32 p10 = *(const u32*)(vb + base + dyo);
    u32 p11 = *(const u32*)(vb + base + dyo + dxo);
    a0 = dot2bf(__builtin_amdgcn_perm(p01, p00, 0x05040100u), r.z, a0);
    a1 = dot2bf(__builtin_amdgcn_perm(p01, p00, 0x07060302u), r.z, a1);
    a0 = dot2bf(__builtin_amdgcn_perm(p11, p10, 0x05040100u), r.w, a0);
    a1 = dot2bf(__builtin_amdgcn_perm(p11, p10, 0x07060302u), r.w, a1);
  }
  u32 pk = (u32)f2bf(a0) | ((u32)f2bf(a1) << 16);
  accv[(b * 2 + qs) * 128 + j] = pk;
}

extern "C" void kernel_launch(void* const* d_in, const int* in_sizes, int n_in,
                              void* d_out, int out_size, void* d_ws, size_t ws_size,
                              hipStream_t stream) {
  const float* query  = (const float*)d_in[0];
  const float* refp   = (const float*)d_in[1];
  const float* pos    = (const float*)d_in[2];
  const float* w_off  = (const float*)d_in[5];
  const float* b_off  = (const float*)d_in[6];
  const float* w_attn = (const float*)d_in[7];
  const float* b_attn = (const float*)d_in[8];
  const float* w_val  = (const float*)d_in[9];
  const float* b_val  = (const float*)d_in[10];
  const float* w_out  = (const float*)d_in[11];
  const float* b_out  = (const float*)d_in[12];
  const float* g1     = (const float*)d_in[13];
  const float* beta1  = (const float*)d_in[14];
  const float* w1     = (const float*)d_in[15];
  const float* b1     = (const float*)d_in[16];
  const float* w2     = (const float*)d_in[17];
  const float* b2     = (const float*)d_in[18];
  const float* g2     = (const float*)d_in[19];
  const float* beta2  = (const float*)d_in[20];

  char* ws = (char*)d_ws;
  u16*   wT    = (u16*)(ws + 0);            //   720,896, live whole launch
  u16*   value = (u16*)(ws + 720896);       // dead after sampler
  u16*   offb  = (u16*)(ws + 22764544);     // dead after sampler
  float* aw    = (float*)(ws + 44808192);   // dead after sampler
  u16*   accb  = (u16*)(ws + 66851840);     // dead after tail

  u16* woffT  = wT;                // 256 rows; wattnT contiguous after (384-row B)
  u16* wvalT  = wT + 98304;
  u16* woutT  = wT + 163840;
  u16* w1T    = wT + 229376;
  u16* w2T    = wT + 294912;

  transpose_all_kernel<<<1408, 256, 0, stream>>>(w_off, w_attn, w_val, w_out, w1, w2, wT);

  const int gh = (LQ + 31) / 32;  // 1346
  valoff_kernel<<<gh, 256, 0, stream>>>(query, pos, wvalT, b_val, woffT, b_off, b_attn,
                                        value, offb, aw, LQ);
  sampler_kernel<<<LQ / 2, 256, 0, stream>>>(refp, offb, aw, value, (u32*)accb);
  tail_fused_kernel<<<gh, 256, 0, stream>>>(accb, woutT, b_out, query, g1, beta1,
                                            w1T, b1, w2T, b2, g2, beta2,
                                            (float*)d_out, LQ);
}